// Round 8
// baseline (249.129 us; speedup 1.0000x reference)
//
#include <hip/hip_runtime.h>
#include <stdint.h>
#include <stddef.h>

// ============================================================================
// MHA block on gfx950, bf16 MFMA pipeline.  B=2,S=2048,D=1024,H=16,hd=64.
// R13: flash latency attack (R12 showed flash is latency-bound: MfmaUtil
// 1.4%, occ 3%, K/V cache-resident, cold dispatch 164us).
//  - flash: 4 waves x 32 q-rows (block 256 thr, grid (32,16) unchanged).
//    Same 16 K/V fragment loads now feed 48 MFMAs (was 24) -> half the
//    load-wait events, 2x arithmetic per event.  K register-prefetched
//    across tiles (kfA/kfB ping-pong, kt-loop unrolled x2, nkv always even,
//    plain local arrays + full unroll -- no lambdas, R9's scratch trigger).
//    V loads issued at tile start, consumed at end (hide under QK^T+SM).
//    launch_bounds(256,2) -> VGPR cap 256 (est ~190 peak).
//  - qkv/oproj/casts: exact R5 (proven local optimum for this session).
// Predictions: flash cold 164.7 -> 75-95us, steady ~40-55; flash WRITE_SIZE
// stays ~9.2MB (spill tripwire); total 240 -> ~200-215us.
// MFMA layouts (verified m89/m91/m120):
//   A-frag: A[m=lane&15][k=(lane>>4)*8+j]  (16B/lane contiguous)
//   B-frag: B[k=(lane>>4)*8+j][n=lane&15] == row-major read of B^T tile
//   C/D:    col=lane&15, row=(lane>>4)*4+reg
// GEMM LDS fragment-major (BK=64): chunk(row,kc) = (row>>4)*128 + kc*16
//   + (row&15), kc = k>>3 in 0..7.  Wave stage base = (w+4*(q&1))*128
//   + 64*(q>>1), lane at +l -> wave-uniform base + lane*16B for
//   global_load_lds; frag reads are lane-contiguous 1KB blocks.
// ============================================================================

typedef __bf16 bf16x8 __attribute__((ext_vector_type(8)));
typedef float  f32x4  __attribute__((ext_vector_type(4)));

__device__ __forceinline__ unsigned short f2b(float f) {
  union { float f; uint32_t u; } v; v.f = f;
  uint32_t u = v.u;
  return (unsigned short)((u + 0x7FFFu + ((u >> 16) & 1u)) >> 16);  // RNE
}

__device__ __forceinline__ void async16(const void* g, void* l) {
  __builtin_amdgcn_global_load_lds(
      (const __attribute__((address_space(1))) void*)g,
      (__attribute__((address_space(3))) void*)l, 16, 0, 0);
}

// ---------------- cast x f32 -> bf16 ----------------
__global__ void cast_kernel(const float* __restrict__ in,
                            unsigned short* __restrict__ out, int n4) {
  int i = blockIdx.x * blockDim.x + threadIdx.x;
  if (i >= n4) return;
  float4 v = ((const float4*)in)[i];
  ushort4 o;
  o.x = f2b(v.x); o.y = f2b(v.y); o.z = f2b(v.z); o.w = f2b(v.w);
  ((ushort4*)out)[i] = o;
}

// ---------------- cast all 4 weight matrices in one launch ----------------
__global__ void cast_w_kernel(const float* __restrict__ wq, const float* __restrict__ wk,
                              const float* __restrict__ wv, const float* __restrict__ wo,
                              unsigned short* __restrict__ wqkv,
                              unsigned short* __restrict__ wobf) {
  int i = blockIdx.x * blockDim.x + threadIdx.x;   // 0 .. 4*2^18-1
  const int sel = i >> 18, k = i & ((1 << 18) - 1);
  const float* src = (sel == 0) ? wq : (sel == 1) ? wk : (sel == 2) ? wv : wo;
  float4 v = ((const float4*)src)[k];
  ushort4 o;
  o.x = f2b(v.x); o.y = f2b(v.y); o.z = f2b(v.z); o.w = f2b(v.w);
  if (sel < 3) ((ushort4*)wqkv)[(size_t)sel * 262144 + k] = o;
  else         ((ushort4*)wobf)[k] = o;
}

// ---------------- fused QKV projection GEMM (+bias, +RoPE on q/k) ----------
// R5-proven version: 128x128 tiles, BK=64, single 32KB LDS, 2 barriers/iter.
// Output layouts:
//   q: [bh][2048][64] row-major (RoPE'd)
//   k: tiled frag-major: [bh][st=32][ chunk L = (d>>3)*64 + (s&63) ][8 of d]
//   v: V^T tiled frag-major: [bh][st=32][ chunk L = ((s&63)>>3)*64 + d ][8 of s]
__global__ __launch_bounds__(256) void qkv_gemm_kernel(
    const unsigned short* __restrict__ A,    // x_bf [4096][1024]
    const unsigned short* __restrict__ W,    // wqkv [3072][1024]
    const float* __restrict__ biasq, const float* __restrict__ biask,
    const float* __restrict__ biasv,
    const float* __restrict__ cp, const float* __restrict__ sp,  // [2048][32]
    unsigned short* __restrict__ qo,
    unsigned short* __restrict__ ko,
    unsigned short* __restrict__ vo)
{
  __shared__ unsigned short As[128 * 64];    // 16 KB
  __shared__ unsigned short Bs[128 * 64];    // 16 KB
  const int tid  = threadIdx.x;
  const int w    = tid >> 6, l = tid & 63;
  const int lm   = l & 15,  quad = l >> 4;
  const int nblk = blockIdx.x;               // 0..23
  const int m0   = blockIdx.y * 128;
  const int n0g  = nblk * 128;
  const int wm   = (w >> 1) * 64, wn = (w & 1) * 64;

  const f32x4 fzero = {0.f, 0.f, 0.f, 0.f};
  f32x4 acc[4][4];
#pragma unroll
  for (int i = 0; i < 4; ++i)
#pragma unroll
    for (int j = 0; j < 4; ++j) acc[i][j] = fzero;

  for (int k0 = 0; k0 < 1024; k0 += 64) {
    __syncthreads();                         // prev iter's ds_reads done
#pragma unroll
    for (int q = 0; q < 4; ++q) {
      const int row = w * 16 + lm + (q & 1) * 64;
      const int kc  = quad + (q >> 1) * 4;
      const size_t ldsb = ((size_t)(w + 4 * (q & 1)) * 128 + 64 * (q >> 1)) * 8;
      async16(A + (size_t)(m0 + row) * 1024 + k0 + kc * 8, As + ldsb);
      async16(W + (size_t)(n0g + row) * 1024 + k0 + kc * 8, Bs + ldsb);
    }
    __syncthreads();                         // drains vmcnt -> tile in LDS
#pragma unroll
    for (int kk = 0; kk < 2; ++kk) {
      bf16x8 af[4], bfc[4];
#pragma unroll
      for (int i = 0; i < 4; ++i)
        af[i] = *(const bf16x8*)(As + (size_t)((((w >> 1) * 4 + i) * 128 + kk * 64 + l)) * 8);
#pragma unroll
      for (int j = 0; j < 4; ++j)
        bfc[j] = *(const bf16x8*)(Bs + (size_t)((((w & 1) * 4 + j) * 128 + kk * 64 + l)) * 8);
#pragma unroll
      for (int i = 0; i < 4; ++i)
#pragma unroll
        for (int j = 0; j < 4; ++j)
          acc[i][j] = __builtin_amdgcn_mfma_f32_16x16x32_bf16(af[i], bfc[j], acc[i][j], 0, 0, 0);
    }
  }

  const int which = nblk >> 3;               // 0=q 1=k 2=v
  const int n0    = (nblk & 7) * 128;
  const float* bias = (which == 0) ? biasq : (which == 1) ? biask : biasv;
#pragma unroll
  for (int i = 0; i < 4; ++i) {
#pragma unroll
    for (int j = 0; j < 4; ++j) {
      const int n = n0 + wn + j * 16 + lm;
      const float bval = bias[n];
      const int h = n >> 6, d = n & 63;
      float vals[4];
#pragma unroll
      for (int r = 0; r < 4; ++r) {
        const int m = m0 + wm + i * 16 + quad * 4 + r;
        const int srow = m & 2047;
        float val = acc[i][j][r] + bval;
        if (which != 2) {
          const float c  = cp[srow * 32 + (d >> 1)];
          const float sn = sp[srow * 32 + (d >> 1)];
          const float part = __shfl_xor(val, 1, 64);
          val = (d & 1) ? (part * sn + val * c) : (val * c - part * sn);
        }
        vals[r] = val;
      }
      const int mbase = m0 + wm + i * 16 + quad * 4;   // 4 consecutive s
      const int b = mbase >> 11, s0 = mbase & 2047;
      const int bh = (b << 4) + h;
      if (which == 0) {
#pragma unroll
        for (int r = 0; r < 4; ++r)
          qo[((size_t)bh * 2048 + s0 + r) * 64 + d] = f2b(vals[r]);
      } else if (which == 1) {
        // tiled: base = (bh*32 + s>>6)*4096 + ((d>>3)*64 + (s&63))*8 + (d&7)
#pragma unroll
        for (int r = 0; r < 4; ++r) {
          const int s = s0 + r;
          ko[((size_t)bh * 32 + (s >> 6)) * 4096 +
             (size_t)(((d >> 3) * 64 + (s & 63))) * 8 + (d & 7)] = f2b(vals[r]);
        }
      } else {
        // V^T tiled, 4 consecutive s -> one uint2 (8B) store
        uint32_t w0 = (uint32_t)f2b(vals[0]) | ((uint32_t)f2b(vals[1]) << 16);
        uint32_t w1 = (uint32_t)f2b(vals[2]) | ((uint32_t)f2b(vals[3]) << 16);
        uint2 pk; pk.x = w0; pk.y = w1;
        *(uint2*)(vo + ((size_t)bh * 32 + (s0 >> 6)) * 4096 +
                  (size_t)((((s0 & 63) >> 3) * 64 + d)) * 8 + (s0 & 7)) = pk;
      }
    }
  }
}

// ---------------- flash attention (R13: 32 rows/wave + K prefetch) --------
// grid (bh=32, 16); block 256 thr = 4 waves; wave w owns q-rows
// qb*128 + w*32 .. +31 (two 16-row halves rh=0,1 sharing the K/V loads).
// S^T = K*Q^T formulation: t in-lane, m = lane&15.  Barrier-free; K/V read
// directly from global (frag-major, cache-resident); K register-prefetched
// one tile ahead; V loaded at tile start, consumed at tile end.
__global__ __launch_bounds__(256, 2) void flash_kernel(
    const unsigned short* __restrict__ Q,    // [32][2048][64] row-major
    const unsigned short* __restrict__ K,    // tiled frag-major (see qkv)
    const unsigned short* __restrict__ VT,   // V^T tiled frag-major
    unsigned short* __restrict__ O)          // [2][2048][1024]
{
  constexpr int PSTRIDE = 72;                // Ps row stride (shorts)
  __shared__ unsigned short Ps[128 * PSTRIDE];   // 18 KB (only LDS)
  const int tid = threadIdx.x;
  const int w = tid >> 6, l = tid & 63, lm = l & 15, quad = l >> 4;
  const int bh = blockIdx.x, qb = 15 - blockIdx.y;   // heavy q-blocks first
  const int wr0 = qb * 128 + w * 32;         // wave's first q-row (global s)

  // Q fragments for both 16-row halves
  bf16x8 aq[2][2];                           // [rh][kc]
#pragma unroll
  for (int rh = 0; rh < 2; ++rh)
#pragma unroll
    for (int kc = 0; kc < 2; ++kc)
      aq[rh][kc] = *(const bf16x8*)(Q + ((size_t)bh * 2048 + wr0 + rh * 16 + lm) * 64
                                    + kc * 32 + quad * 8);

  const f32x4 fzero = {0.f, 0.f, 0.f, 0.f};
  f32x4 Oacc[2][4];
#pragma unroll
  for (int rh = 0; rh < 2; ++rh)
#pragma unroll
    for (int jo = 0; jo < 4; ++jo) Oacc[rh][jo] = fzero;
  float m_i[2] = {-1e30f, -1e30f}, l_i[2] = {0.f, 0.f};

  const int nkv = 2 * qb + 2;                // even

  // one kv-tile: V-load -> QK^T(2 halves) -> softmax -> PV.  KF = prefetched
  // K fragments for this tile.  All arrays statically indexed (full unroll).
#define FLASH_TILE(KT, KF)                                                    \
  {                                                                           \
    const size_t tbv_ = ((size_t)bh * 32 + (KT)) * 4096;                      \
    bf16x8 vf[2][4];                                                          \
    _Pragma("unroll")                                                         \
    for (int kc = 0; kc < 2; ++kc)                                            \
      _Pragma("unroll")                                                       \
      for (int jo = 0; jo < 4; ++jo)                                          \
        vf[kc][jo] = *(const bf16x8*)(VT + tbv_ +                             \
            (size_t)(((kc * 4 + quad) * 64 + jo * 16 + lm)) * 8);             \
    float alpha2[2];                                                          \
    _Pragma("unroll")                                                         \
    for (int rh = 0; rh < 2; ++rh) {                                          \
      f32x4 Sc[4];                                                            \
      _Pragma("unroll")                                                       \
      for (int tb = 0; tb < 4; ++tb) Sc[tb] = fzero;                          \
      _Pragma("unroll")                                                       \
      for (int kc = 0; kc < 2; ++kc)                                          \
        _Pragma("unroll")                                                     \
        for (int tb = 0; tb < 4; ++tb)                                        \
          Sc[tb] = __builtin_amdgcn_mfma_f32_16x16x32_bf16(                   \
              KF[kc][tb], aq[rh][kc], Sc[tb], 0, 0, 0);                       \
      const int mrow = wr0 + rh * 16 + lm;                                    \
      const bool needmask = ((KT) * 64 + 63 > wr0 + rh * 16);                 \
      const int mrel = mrow - (KT) * 64;                                      \
      float mx = -1e30f;                                                      \
      _Pragma("unroll")                                                       \
      for (int tb = 0; tb < 4; ++tb)                                          \
        _Pragma("unroll")                                                     \
        for (int r = 0; r < 4; ++r) {                                         \
          float s = Sc[tb][r] * 0.125f;                                       \
          if (needmask && (tb * 16 + quad * 4 + r > mrel)) s = -1e30f;        \
          Sc[tb][r] = s;                                                      \
          mx = fmaxf(mx, s);                                                  \
        }                                                                     \
      mx = fmaxf(mx, __shfl_xor(mx, 16, 64));                                 \
      mx = fmaxf(mx, __shfl_xor(mx, 32, 64));                                 \
      const float mnew = fmaxf(m_i[rh], mx);                                  \
      alpha2[rh] = __expf(m_i[rh] - mnew);                                    \
      m_i[rh] = mnew;                                                         \
      float ps = 0.f;                                                         \
      _Pragma("unroll")                                                       \
      for (int tb = 0; tb < 4; ++tb) {                                        \
        float p0 = __expf(Sc[tb][0] - mnew), p1 = __expf(Sc[tb][1] - mnew);   \
        float p2 = __expf(Sc[tb][2] - mnew), p3 = __expf(Sc[tb][3] - mnew);   \
        ps += (p0 + p1) + (p2 + p3);                                          \
        uint2 pk;                                                             \
        pk.x = (uint32_t)f2b(p0) | ((uint32_t)f2b(p1) << 16);                 \
        pk.y = (uint32_t)f2b(p2) | ((uint32_t)f2b(p3) << 16);                 \
        *(uint2*)(Ps + (size_t)(w * 32 + rh * 16 + lm) * PSTRIDE +            \
                  tb * 16 + quad * 4) = pk;                                   \
      }                                                                       \
      ps += __shfl_xor(ps, 16, 64);                                           \
      ps += __shfl_xor(ps, 32, 64);                                           \
      l_i[rh] = l_i[rh] * alpha2[rh] + ps;                                    \
    }                                                                         \
    _Pragma("unroll")                                                         \
    for (int rh = 0; rh < 2; ++rh) {                                          \
      float af4[4];                                                           \
      _Pragma("unroll")                                                       \
      for (int r = 0; r < 4; ++r)                                             \
        af4[r] = __shfl(alpha2[rh], quad * 4 + r, 64);                        \
      _Pragma("unroll")                                                       \
      for (int jo = 0; jo < 4; ++jo)                                          \
        _Pragma("unroll")                                                     \
        for (int r = 0; r < 4; ++r) Oacc[rh][jo][r] *= af4[r];                \
      _Pragma("unroll")                                                       \
      for (int kc = 0; kc < 2; ++kc) {                                        \
        bf16x8 ap = *(const bf16x8*)(Ps +                                     \
            (size_t)(w * 32 + rh * 16 + lm) * PSTRIDE + kc * 32 + quad * 8);  \
        _Pragma("unroll")                                                     \
        for (int jo = 0; jo < 4; ++jo)                                        \
          Oacc[rh][jo] = __builtin_amdgcn_mfma_f32_16x16x32_bf16(             \
              ap, vf[kc][jo], Oacc[rh][jo], 0, 0, 0);                         \
      }                                                                       \
    }                                                                         \
  }

#define LOADK(KF, KT)                                                         \
  {                                                                           \
    const size_t tbk_ = ((size_t)bh * 32 + (KT)) * 4096;                      \
    _Pragma("unroll")                                                         \
    for (int kc = 0; kc < 2; ++kc)                                            \
      _Pragma("unroll")                                                       \
      for (int tb = 0; tb < 4; ++tb)                                          \
        KF[kc][tb] = *(const bf16x8*)(K + tbk_ +                              \
            (size_t)(((kc * 4 + quad) * 64 + tb * 16 + lm)) * 8);             \
  }

  bf16x8 kfA[2][4], kfB[2][4];
  LOADK(kfA, 0);
#pragma unroll 1
  for (int kt = 0; kt < nkv; kt += 2) {
    LOADK(kfB, kt + 1);                      // prefetch next tile's K
    FLASH_TILE(kt, kfA);
    if (kt + 2 < nkv) LOADK(kfA, kt + 2);    // prefetch tile after next
    FLASH_TILE(kt + 1, kfB);
  }
#undef FLASH_TILE
#undef LOADK

  // epilogue: normalize, write o_bf (b, s, h*64+d)
  const int b = bh >> 4, h = bh & 15;
#pragma unroll
  for (int rh = 0; rh < 2; ++rh) {
    float lf[4];
#pragma unroll
    for (int r = 0; r < 4; ++r) lf[r] = 1.0f / __shfl(l_i[rh], quad * 4 + r, 64);
#pragma unroll
    for (int jo = 0; jo < 4; ++jo)
#pragma unroll
      for (int r = 0; r < 4; ++r) {
        const int s   = wr0 + rh * 16 + quad * 4 + r;
        const int col = h * 64 + jo * 16 + lm;
        O[((size_t)b * 2048 + s) * 1024 + col] = f2b(Oacc[rh][jo][r] * lf[r]);
      }
  }
}

// ---------------- output projection GEMM (R5-proven version) ----------------
// out[4096,1024] = Obf[4096,1024] @ Wo[1024,1024]^T + bias (fp32 out).
// 64x128 tiles, BK=64, 512 blocks (2/CU).  Wave w covers cols w*32..w*32+31.
__global__ __launch_bounds__(256) void oproj_gemm_kernel(
    const unsigned short* __restrict__ A,    // o_bf [4096][1024]
    const unsigned short* __restrict__ W,    // wo_bf [1024][1024]
    const float* __restrict__ bias,
    float* __restrict__ out)
{
  __shared__ unsigned short As[64 * 64];     // 8 KB
  __shared__ unsigned short Bs[128 * 64];    // 16 KB
  const int tid = threadIdx.x;
  const int w = tid >> 6, l = tid & 63;
  const int lm = l & 15, quad = l >> 4;
  const int m0 = blockIdx.y * 64;
  const int n0 = blockIdx.x * 128;

  const f32x4 fzero = {0.f, 0.f, 0.f, 0.f};
  f32x4 acc[4][2];
#pragma unroll
  for (int i = 0; i < 4; ++i)
#pragma unroll
    for (int j = 0; j < 2; ++j) acc[i][j] = fzero;

  for (int k0 = 0; k0 < 1024; k0 += 64) {
    __syncthreads();
    // A: 64 rows x 8 kc = 512 chunks; 2 per thread
#pragma unroll
    for (int q = 0; q < 2; ++q) {
      const int row = w * 16 + lm;
      const int kc  = quad + 4 * q;
      async16(A + (size_t)(m0 + row) * 1024 + k0 + kc * 8,
              As + ((size_t)w * 128 + 64 * q) * 8);
    }
    // B: 128 rows x 8 kc = 1024 chunks; 4 per thread
#pragma unroll
    for (int q = 0; q < 4; ++q) {
      const int row = w * 16 + lm + (q & 1) * 64;
      const int kc  = quad + 4 * (q >> 1);
      async16(W + (size_t)(n0 + row) * 1024 + k0 + kc * 8,
              Bs + ((size_t)(w + 4 * (q & 1)) * 128 + 64 * (q >> 1)) * 8);
    }
    __syncthreads();
#pragma unroll
    for (int kk = 0; kk < 2; ++kk) {
      bf16x8 af[4], bfc[2];
#pragma unroll
      for (int i = 0; i < 4; ++i)
        af[i] = *(const bf16x8*)(As + (size_t)((i * 128 + kk * 64 + l)) * 8);
#pragma unroll
      for (int j = 0; j < 2; ++j)
        bfc[j] = *(const bf16x8*)(Bs + (size_t)(((w * 2 + j) * 128 + kk * 64 + l)) * 8);
#pragma unroll
      for (int i = 0; i < 4; ++i)
#pragma unroll
        for (int j = 0; j < 2; ++j)
          acc[i][j] = __builtin_amdgcn_mfma_f32_16x16x32_bf16(af[i], bfc[j], acc[i][j], 0, 0, 0);
    }
  }

#pragma unroll
  for (int i = 0; i < 4; ++i) {
#pragma unroll
    for (int j = 0; j < 2; ++j) {
      const int n = n0 + w * 32 + j * 16 + lm;
      const float bval = bias[n];
#pragma unroll
      for (int r = 0; r < 4; ++r) {
        const int m = m0 + i * 16 + quad * 4 + r;
        out[(size_t)m * 1024 + n] = acc[i][j][r] + bval;
      }
    }
  }
}

// ---------------- host launch ----------------
extern "C" void kernel_launch(void* const* d_in, const int* in_sizes, int n_in,
                              void* d_out, int out_size, void* d_ws, size_t ws_size,
                              hipStream_t stream) {
  (void)in_sizes; (void)n_in; (void)out_size; (void)ws_size;
  const float* x  = (const float*)d_in[0];
  const float* cp = (const float*)d_in[1];
  const float* sp = (const float*)d_in[2];
  const float* wq = (const float*)d_in[3];
  const float* bq = (const float*)d_in[4];
  const float* wk = (const float*)d_in[5];
  const float* bk = (const float*)d_in[6];
  const float* wv = (const float*)d_in[7];
  const float* bv = (const float*)d_in[8];
  const float* wo = (const float*)d_in[9];
  const float* bo = (const float*)d_in[10];
  float* out = (float*)d_out;

  unsigned short* xbf  = (unsigned short*)d_ws;          // 4M shorts
  unsigned short* wqkv = xbf  + (size_t)4 * 1024 * 1024; // 3M
  unsigned short* wobf = wqkv + (size_t)3 * 1024 * 1024; // 1M
  unsigned short* qbf  = wobf + (size_t)1 * 1024 * 1024; // 4M (bh,s,d)
  unsigned short* kbf  = qbf  + (size_t)4 * 1024 * 1024; // 4M (tiled frag-major)
  unsigned short* vbf  = kbf  + (size_t)4 * 1024 * 1024; // 4M (V^T tiled)
  unsigned short* obf  = vbf  + (size_t)4 * 1024 * 1024; // 4M (b,s,h*64+d)

  hipLaunchKernelGGL(cast_kernel, dim3(4096), dim3(256), 0, stream, x, xbf, 1048576);
  hipLaunchKernelGGL(cast_w_kernel, dim3(4096), dim3(256), 0, stream,
                     wq, wk, wv, wo, wqkv, wobf);

  hipLaunchKernelGGL(qkv_gemm_kernel, dim3(24, 32), dim3(256), 0, stream,
                     xbf, wqkv, bq, bk, bv, cp, sp, qbf, kbf, vbf);
  hipLaunchKernelGGL(flash_kernel, dim3(32, 16), dim3(256), 0, stream,
                     qbf, kbf, vbf, obf);
  hipLaunchKernelGGL(oproj_gemm_kernel, dim3(8, 64), dim3(256), 0, stream,
                     obf, wobf, bo, out);
}

// Round 9
// 226.743 us; speedup vs baseline: 1.0987x; 1.0987x over previous
//
#include <hip/hip_runtime.h>
#include <stdint.h>
#include <stddef.h>

// ============================================================================
// MHA block on gfx950, bf16 MFMA pipeline.  B=2,S=2048,D=1024,H=16,hd=64.
// R14: flash VALU/TLP attack (R13 counters: VALUBusy 31% vs MfmaUtil 8.4%,
// occupancy 14% ~= 1 wave/SIMD -- softmax VALU chain runs unoverlapped).
//  - flash: 64-row blocks (4 waves x 16 q-rows), grid (32,32)=1024 blocks ->
//    4 blocks/CU = 16 waves/CU = 4 waves/SIMD (launch_bounds(256,4), VGPR
//    est ~119 < 128 cap; cross-tile K ping-pong dropped to pay for it --
//    inter-wave TLP replaces intra-wave prefetch; K/V are cache-resident).
//  - Mask hoisted: only diagonal tile kt==qt masks; tiles 0..qt-1 mask-free.
//  - T13 defer-max (THR=8): skip alpha-exp + 4 shuffles + 16 rescale mults
//    when __all(mx - m_i <= 8) -- common case after first tile.
//  - qkv/oproj/casts: exact R5 (proven local optimum this session).
// Predictions: flash 83 -> 45-55us (occ ~30%, VALUBusy ~55%, MfmaUtil ~14%);
// total 249 -> ~205-215us.
// MFMA layouts (verified m89/m91/m120):
//   A-frag: A[m=lane&15][k=(lane>>4)*8+j]  (16B/lane contiguous)
//   B-frag: B[k=(lane>>4)*8+j][n=lane&15] == row-major read of B^T tile
//   C/D:    col=lane&15, row=(lane>>4)*4+reg
// GEMM LDS fragment-major (BK=64): chunk(row,kc) = (row>>4)*128 + kc*16
//   + (row&15), kc = k>>3 in 0..7.  Wave stage base = (w+4*(q&1))*128
//   + 64*(q>>1), lane at +l -> wave-uniform base + lane*16B for
//   global_load_lds; frag reads are lane-contiguous 1KB blocks.
// ============================================================================

typedef __bf16 bf16x8 __attribute__((ext_vector_type(8)));
typedef float  f32x4  __attribute__((ext_vector_type(4)));

__device__ __forceinline__ unsigned short f2b(float f) {
  union { float f; uint32_t u; } v; v.f = f;
  uint32_t u = v.u;
  return (unsigned short)((u + 0x7FFFu + ((u >> 16) & 1u)) >> 16);  // RNE
}

__device__ __forceinline__ void async16(const void* g, void* l) {
  __builtin_amdgcn_global_load_lds(
      (const __attribute__((address_space(1))) void*)g,
      (__attribute__((address_space(3))) void*)l, 16, 0, 0);
}

// ---------------- cast x f32 -> bf16 ----------------
__global__ void cast_kernel(const float* __restrict__ in,
                            unsigned short* __restrict__ out, int n4) {
  int i = blockIdx.x * blockDim.x + threadIdx.x;
  if (i >= n4) return;
  float4 v = ((const float4*)in)[i];
  ushort4 o;
  o.x = f2b(v.x); o.y = f2b(v.y); o.z = f2b(v.z); o.w = f2b(v.w);
  ((ushort4*)out)[i] = o;
}

// ---------------- cast all 4 weight matrices in one launch ----------------
__global__ void cast_w_kernel(const float* __restrict__ wq, const float* __restrict__ wk,
                              const float* __restrict__ wv, const float* __restrict__ wo,
                              unsigned short* __restrict__ wqkv,
                              unsigned short* __restrict__ wobf) {
  int i = blockIdx.x * blockDim.x + threadIdx.x;   // 0 .. 4*2^18-1
  const int sel = i >> 18, k = i & ((1 << 18) - 1);
  const float* src = (sel == 0) ? wq : (sel == 1) ? wk : (sel == 2) ? wv : wo;
  float4 v = ((const float4*)src)[k];
  ushort4 o;
  o.x = f2b(v.x); o.y = f2b(v.y); o.z = f2b(v.z); o.w = f2b(v.w);
  if (sel < 3) ((ushort4*)wqkv)[(size_t)sel * 262144 + k] = o;
  else         ((ushort4*)wobf)[k] = o;
}

// ---------------- fused QKV projection GEMM (+bias, +RoPE on q/k) ----------
// R5-proven version: 128x128 tiles, BK=64, single 32KB LDS, 2 barriers/iter.
// Output layouts:
//   q: [bh][2048][64] row-major (RoPE'd)
//   k: tiled frag-major: [bh][st=32][ chunk L = (d>>3)*64 + (s&63) ][8 of d]
//   v: V^T tiled frag-major: [bh][st=32][ chunk L = ((s&63)>>3)*64 + d ][8 of s]
__global__ __launch_bounds__(256) void qkv_gemm_kernel(
    const unsigned short* __restrict__ A,    // x_bf [4096][1024]
    const unsigned short* __restrict__ W,    // wqkv [3072][1024]
    const float* __restrict__ biasq, const float* __restrict__ biask,
    const float* __restrict__ biasv,
    const float* __restrict__ cp, const float* __restrict__ sp,  // [2048][32]
    unsigned short* __restrict__ qo,
    unsigned short* __restrict__ ko,
    unsigned short* __restrict__ vo)
{
  __shared__ unsigned short As[128 * 64];    // 16 KB
  __shared__ unsigned short Bs[128 * 64];    // 16 KB
  const int tid  = threadIdx.x;
  const int w    = tid >> 6, l = tid & 63;
  const int lm   = l & 15,  quad = l >> 4;
  const int nblk = blockIdx.x;               // 0..23
  const int m0   = blockIdx.y * 128;
  const int n0g  = nblk * 128;
  const int wm   = (w >> 1) * 64, wn = (w & 1) * 64;

  const f32x4 fzero = {0.f, 0.f, 0.f, 0.f};
  f32x4 acc[4][4];
#pragma unroll
  for (int i = 0; i < 4; ++i)
#pragma unroll
    for (int j = 0; j < 4; ++j) acc[i][j] = fzero;

  for (int k0 = 0; k0 < 1024; k0 += 64) {
    __syncthreads();                         // prev iter's ds_reads done
#pragma unroll
    for (int q = 0; q < 4; ++q) {
      const int row = w * 16 + lm + (q & 1) * 64;
      const int kc  = quad + (q >> 1) * 4;
      const size_t ldsb = ((size_t)(w + 4 * (q & 1)) * 128 + 64 * (q >> 1)) * 8;
      async16(A + (size_t)(m0 + row) * 1024 + k0 + kc * 8, As + ldsb);
      async16(W + (size_t)(n0g + row) * 1024 + k0 + kc * 8, Bs + ldsb);
    }
    __syncthreads();                         // drains vmcnt -> tile in LDS
#pragma unroll
    for (int kk = 0; kk < 2; ++kk) {
      bf16x8 af[4], bfc[4];
#pragma unroll
      for (int i = 0; i < 4; ++i)
        af[i] = *(const bf16x8*)(As + (size_t)((((w >> 1) * 4 + i) * 128 + kk * 64 + l)) * 8);
#pragma unroll
      for (int j = 0; j < 4; ++j)
        bfc[j] = *(const bf16x8*)(Bs + (size_t)((((w & 1) * 4 + j) * 128 + kk * 64 + l)) * 8);
#pragma unroll
      for (int i = 0; i < 4; ++i)
#pragma unroll
        for (int j = 0; j < 4; ++j)
          acc[i][j] = __builtin_amdgcn_mfma_f32_16x16x32_bf16(af[i], bfc[j], acc[i][j], 0, 0, 0);
    }
  }

  const int which = nblk >> 3;               // 0=q 1=k 2=v
  const int n0    = (nblk & 7) * 128;
  const float* bias = (which == 0) ? biasq : (which == 1) ? biask : biasv;
#pragma unroll
  for (int i = 0; i < 4; ++i) {
#pragma unroll
    for (int j = 0; j < 4; ++j) {
      const int n = n0 + wn + j * 16 + lm;
      const float bval = bias[n];
      const int h = n >> 6, d = n & 63;
      float vals[4];
#pragma unroll
      for (int r = 0; r < 4; ++r) {
        const int m = m0 + wm + i * 16 + quad * 4 + r;
        const int srow = m & 2047;
        float val = acc[i][j][r] + bval;
        if (which != 2) {
          const float c  = cp[srow * 32 + (d >> 1)];
          const float sn = sp[srow * 32 + (d >> 1)];
          const float part = __shfl_xor(val, 1, 64);
          val = (d & 1) ? (part * sn + val * c) : (val * c - part * sn);
        }
        vals[r] = val;
      }
      const int mbase = m0 + wm + i * 16 + quad * 4;   // 4 consecutive s
      const int b = mbase >> 11, s0 = mbase & 2047;
      const int bh = (b << 4) + h;
      if (which == 0) {
#pragma unroll
        for (int r = 0; r < 4; ++r)
          qo[((size_t)bh * 2048 + s0 + r) * 64 + d] = f2b(vals[r]);
      } else if (which == 1) {
        // tiled: base = (bh*32 + s>>6)*4096 + ((d>>3)*64 + (s&63))*8 + (d&7)
#pragma unroll
        for (int r = 0; r < 4; ++r) {
          const int s = s0 + r;
          ko[((size_t)bh * 32 + (s >> 6)) * 4096 +
             (size_t)(((d >> 3) * 64 + (s & 63))) * 8 + (d & 7)] = f2b(vals[r]);
        }
      } else {
        // V^T tiled, 4 consecutive s -> one uint2 (8B) store
        uint32_t w0 = (uint32_t)f2b(vals[0]) | ((uint32_t)f2b(vals[1]) << 16);
        uint32_t w1 = (uint32_t)f2b(vals[2]) | ((uint32_t)f2b(vals[3]) << 16);
        uint2 pk; pk.x = w0; pk.y = w1;
        *(uint2*)(vo + ((size_t)bh * 32 + (s0 >> 6)) * 4096 +
                  (size_t)((((s0 & 63) >> 3) * 64 + d)) * 8 + (s0 & 7)) = pk;
      }
    }
  }
}

// ---------------- flash attention (R14: 16 rows/wave, 4 blk/CU) -----------
// grid (bh=32, 32); block 256 thr = 4 waves; block covers 64 q-rows
// (qt*64 .. +63), wave w owns rows qt*64 + w*16 + lm.  Barrier-free; K/V
// direct from global (frag-major, cache-resident).  Mask only on the
// diagonal tile (kt == qt).  T13 defer-max (THR=8) skips rescale.
__global__ __launch_bounds__(256, 4) void flash_kernel(
    const unsigned short* __restrict__ Q,    // [32][2048][64] row-major
    const unsigned short* __restrict__ K,    // tiled frag-major (see qkv)
    const unsigned short* __restrict__ VT,   // V^T tiled frag-major
    unsigned short* __restrict__ O)          // [2][2048][1024]
{
  constexpr int PSTRIDE = 72;                // Ps row stride (shorts)
  __shared__ unsigned short Ps[64 * PSTRIDE];    // 9 KB (only LDS)
  const int tid = threadIdx.x;
  const int w = tid >> 6, l = tid & 63, lm = l & 15, quad = l >> 4;
  const int bh = blockIdx.x, qt = 31 - (int)blockIdx.y;  // heavy first
  const int row0 = qt * 64 + w * 16;         // wave's first q-row

  // Q fragments: lane reads row row0+lm, 8 d at kc*32+quad*8
  bf16x8 aq[2];
#pragma unroll
  for (int kc = 0; kc < 2; ++kc)
    aq[kc] = *(const bf16x8*)(Q + ((size_t)bh * 2048 + row0 + lm) * 64 + kc * 32 + quad * 8);

  const f32x4 fzero = {0.f, 0.f, 0.f, 0.f};
  f32x4 Oacc[4];
#pragma unroll
  for (int jo = 0; jo < 4; ++jo) Oacc[jo] = fzero;
  float m_i = -1e30f, l_i = 0.f;

  const int nkv = qt + 1;

  // ---- unmasked tiles 0 .. qt-1 ----
#pragma unroll 1
  for (int kt = 0; kt < nkv - 1; ++kt) {
    const size_t tbase = ((size_t)bh * 32 + kt) * 4096;
    bf16x8 kf[2][4], vf[2][4];
#pragma unroll
    for (int kc = 0; kc < 2; ++kc)
#pragma unroll
      for (int tb = 0; tb < 4; ++tb) {
        const size_t off = tbase + (size_t)(((kc * 4 + quad) * 64 + tb * 16 + lm)) * 8;
        kf[kc][tb] = *(const bf16x8*)(K + off);
        vf[kc][tb] = *(const bf16x8*)(VT + off);
      }
    // S^T = K * Q^T : Sc[tb] holds t = tb*16+quad*4+r (rows), m = lm (col)
    f32x4 Sc[4];
#pragma unroll
    for (int tb = 0; tb < 4; ++tb) Sc[tb] = fzero;
#pragma unroll
    for (int kc = 0; kc < 2; ++kc)
#pragma unroll
      for (int tb = 0; tb < 4; ++tb)
        Sc[tb] = __builtin_amdgcn_mfma_f32_16x16x32_bf16(kf[kc][tb], aq[kc], Sc[tb], 0, 0, 0);

    float mx = -1e30f;
#pragma unroll
    for (int tb = 0; tb < 4; ++tb)
#pragma unroll
      for (int r = 0; r < 4; ++r) {
        float s = Sc[tb][r] * 0.125f;        // 1/sqrt(64)
        Sc[tb][r] = s;
        mx = fmaxf(mx, s);
      }
    mx = fmaxf(mx, __shfl_xor(mx, 16, 64));
    mx = fmaxf(mx, __shfl_xor(mx, 32, 64));

    // T13 defer-max: skip rescale when all rows grew by <= 8
    const bool skip = (bool)__all(mx - m_i <= 8.0f);
    float alpha = 1.f;
    if (!skip) {
      const float mnew = fmaxf(m_i, mx);
      alpha = __expf(m_i - mnew);
      m_i = mnew;
    }
    const float mref = m_i;

    float ps = 0.f;
#pragma unroll
    for (int tb = 0; tb < 4; ++tb) {
      float p0 = __expf(Sc[tb][0] - mref), p1 = __expf(Sc[tb][1] - mref);
      float p2 = __expf(Sc[tb][2] - mref), p3 = __expf(Sc[tb][3] - mref);
      ps += (p0 + p1) + (p2 + p3);
      uint2 pk;
      pk.x = (uint32_t)f2b(p0) | ((uint32_t)f2b(p1) << 16);
      pk.y = (uint32_t)f2b(p2) | ((uint32_t)f2b(p3) << 16);
      *(uint2*)(Ps + (size_t)(w * 16 + lm) * PSTRIDE + tb * 16 + quad * 4) = pk;
    }
    ps += __shfl_xor(ps, 16, 64);
    ps += __shfl_xor(ps, 32, 64);
    if (skip) {
      l_i += ps;
    } else {
      l_i = l_i * alpha + ps;
      float af4[4];
#pragma unroll
      for (int r = 0; r < 4; ++r) af4[r] = __shfl(alpha, quad * 4 + r, 64);
#pragma unroll
      for (int jo = 0; jo < 4; ++jo)
#pragma unroll
        for (int r = 0; r < 4; ++r) Oacc[jo][r] *= af4[r];
    }

    // O += P V
#pragma unroll
    for (int kc = 0; kc < 2; ++kc) {
      bf16x8 ap = *(const bf16x8*)(Ps + (size_t)(w * 16 + lm) * PSTRIDE + kc * 32 + quad * 8);
#pragma unroll
      for (int jo = 0; jo < 4; ++jo)
        Oacc[jo] = __builtin_amdgcn_mfma_f32_16x16x32_bf16(ap, vf[kc][jo], Oacc[jo], 0, 0, 0);
    }
  }

  // ---- diagonal (masked) tile kt = qt ----
  {
    const size_t tbase = ((size_t)bh * 32 + qt) * 4096;
    bf16x8 kf[2][4], vf[2][4];
#pragma unroll
    for (int kc = 0; kc < 2; ++kc)
#pragma unroll
      for (int tb = 0; tb < 4; ++tb) {
        const size_t off = tbase + (size_t)(((kc * 4 + quad) * 64 + tb * 16 + lm)) * 8;
        kf[kc][tb] = *(const bf16x8*)(K + off);
        vf[kc][tb] = *(const bf16x8*)(VT + off);
      }
    f32x4 Sc[4];
#pragma unroll
    for (int tb = 0; tb < 4; ++tb) Sc[tb] = fzero;
#pragma unroll
    for (int kc = 0; kc < 2; ++kc)
#pragma unroll
      for (int tb = 0; tb < 4; ++tb)
        Sc[tb] = __builtin_amdgcn_mfma_f32_16x16x32_bf16(kf[kc][tb], aq[kc], Sc[tb], 0, 0, 0);

    const int mrel = w * 16 + lm;            // mask t-index > mrel
    float mx = -1e30f;
#pragma unroll
    for (int tb = 0; tb < 4; ++tb)
#pragma unroll
      for (int r = 0; r < 4; ++r) {
        float s = Sc[tb][r] * 0.125f;
        if (tb * 16 + quad * 4 + r > mrel) s = -1e30f;
        Sc[tb][r] = s;
        mx = fmaxf(mx, s);
      }
    mx = fmaxf(mx, __shfl_xor(mx, 16, 64));
    mx = fmaxf(mx, __shfl_xor(mx, 32, 64));
    const float mnew  = fmaxf(m_i, mx);
    const float alpha = __expf(m_i - mnew);
    m_i = mnew;

    float ps = 0.f;
#pragma unroll
    for (int tb = 0; tb < 4; ++tb) {
      float p0 = __expf(Sc[tb][0] - mnew), p1 = __expf(Sc[tb][1] - mnew);
      float p2 = __expf(Sc[tb][2] - mnew), p3 = __expf(Sc[tb][3] - mnew);
      ps += (p0 + p1) + (p2 + p3);
      uint2 pk;
      pk.x = (uint32_t)f2b(p0) | ((uint32_t)f2b(p1) << 16);
      pk.y = (uint32_t)f2b(p2) | ((uint32_t)f2b(p3) << 16);
      *(uint2*)(Ps + (size_t)(w * 16 + lm) * PSTRIDE + tb * 16 + quad * 4) = pk;
    }
    ps += __shfl_xor(ps, 16, 64);
    ps += __shfl_xor(ps, 32, 64);
    l_i = l_i * alpha + ps;

    float af4[4];
#pragma unroll
    for (int r = 0; r < 4; ++r) af4[r] = __shfl(alpha, quad * 4 + r, 64);
#pragma unroll
    for (int jo = 0; jo < 4; ++jo)
#pragma unroll
      for (int r = 0; r < 4; ++r) Oacc[jo][r] *= af4[r];

#pragma unroll
    for (int kc = 0; kc < 2; ++kc) {
      bf16x8 ap = *(const bf16x8*)(Ps + (size_t)(w * 16 + lm) * PSTRIDE + kc * 32 + quad * 8);
#pragma unroll
      for (int jo = 0; jo < 4; ++jo)
        Oacc[jo] = __builtin_amdgcn_mfma_f32_16x16x32_bf16(ap, vf[kc][jo], Oacc[jo], 0, 0, 0);
    }
  }

  // epilogue: normalize, write o_bf (b, s, h*64+d)
  float lf[4];
#pragma unroll
  for (int r = 0; r < 4; ++r) lf[r] = 1.0f / __shfl(l_i, quad * 4 + r, 64);
  const int b = bh >> 4, h = bh & 15;
#pragma unroll
  for (int jo = 0; jo < 4; ++jo)
#pragma unroll
    for (int r = 0; r < 4; ++r) {
      const int s   = row0 + quad * 4 + r;
      const int col = h * 64 + jo * 16 + lm;
      O[((size_t)b * 2048 + s) * 1024 + col] = f2b(Oacc[jo][r] * lf[r]);
    }
}

// ---------------- output projection GEMM (R5-proven version) ----------------
// out[4096,1024] = Obf[4096,1024] @ Wo[1024,1024]^T + bias (fp32 out).
// 64x128 tiles, BK=64, 512 blocks (2/CU).  Wave w covers cols w*32..w*32+31.
__global__ __launch_bounds__(256) void oproj_gemm_kernel(
    const unsigned short* __restrict__ A,    // o_bf [4096][1024]
    const unsigned short* __restrict__ W,    // wo_bf [1024][1024]
    const float* __restrict__ bias,
    float* __restrict__ out)
{
  __shared__ unsigned short As[64 * 64];     // 8 KB
  __shared__ unsigned short Bs[128 * 64];    // 16 KB
  const int tid = threadIdx.x;
  const int w = tid >> 6, l = tid & 63;
  const int lm = l & 15, quad = l >> 4;
  const int m0 = blockIdx.y * 64;
  const int n0 = blockIdx.x * 128;

  const f32x4 fzero = {0.f, 0.f, 0.f, 0.f};
  f32x4 acc[4][2];
#pragma unroll
  for (int i = 0; i < 4; ++i)
#pragma unroll
    for (int j = 0; j < 2; ++j) acc[i][j] = fzero;

  for (int k0 = 0; k0 < 1024; k0 += 64) {
    __syncthreads();
    // A: 64 rows x 8 kc = 512 chunks; 2 per thread
#pragma unroll
    for (int q = 0; q < 2; ++q) {
      const int row = w * 16 + lm;
      const int kc  = quad + 4 * q;
      async16(A + (size_t)(m0 + row) * 1024 + k0 + kc * 8,
              As + ((size_t)w * 128 + 64 * q) * 8);
    }
    // B: 128 rows x 8 kc = 1024 chunks; 4 per thread
#pragma unroll
    for (int q = 0; q < 4; ++q) {
      const int row = w * 16 + lm + (q & 1) * 64;
      const int kc  = quad + 4 * (q >> 1);
      async16(W + (size_t)(n0 + row) * 1024 + k0 + kc * 8,
              Bs + ((size_t)(w + 4 * (q & 1)) * 128 + 64 * (q >> 1)) * 8);
    }
    __syncthreads();
#pragma unroll
    for (int kk = 0; kk < 2; ++kk) {
      bf16x8 af[4], bfc[2];
#pragma unroll
      for (int i = 0; i < 4; ++i)
        af[i] = *(const bf16x8*)(As + (size_t)((i * 128 + kk * 64 + l)) * 8);
#pragma unroll
      for (int j = 0; j < 2; ++j)
        bfc[j] = *(const bf16x8*)(Bs + (size_t)(((w * 2 + j) * 128 + kk * 64 + l)) * 8);
#pragma unroll
      for (int i = 0; i < 4; ++i)
#pragma unroll
        for (int j = 0; j < 2; ++j)
          acc[i][j] = __builtin_amdgcn_mfma_f32_16x16x32_bf16(af[i], bfc[j], acc[i][j], 0, 0, 0);
    }
  }

#pragma unroll
  for (int i = 0; i < 4; ++i) {
#pragma unroll
    for (int j = 0; j < 2; ++j) {
      const int n = n0 + w * 32 + j * 16 + lm;
      const float bval = bias[n];
#pragma unroll
      for (int r = 0; r < 4; ++r) {
        const int m = m0 + i * 16 + quad * 4 + r;
        out[(size_t)m * 1024 + n] = acc[i][j][r] + bval;
      }
    }
  }
}

// ---------------- host launch ----------------
extern "C" void kernel_launch(void* const* d_in, const int* in_sizes, int n_in,
                              void* d_out, int out_size, void* d_ws, size_t ws_size,
                              hipStream_t stream) {
  (void)in_sizes; (void)n_in; (void)out_size; (void)ws_size;
  const float* x  = (const float*)d_in[0];
  const float* cp = (const float*)d_in[1];
  const float* sp = (const float*)d_in[2];
  const float* wq = (const float*)d_in[3];
  const float* bq = (const float*)d_in[4];
  const float* wk = (const float*)d_in[5];
  const float* bk = (const float*)d_in[6];
  const float* wv = (const float*)d_in[7];
  const float* bv = (const float*)d_in[8];
  const float* wo = (const float*)d_in[9];
  const float* bo = (const float*)d_in[10];
  float* out = (float*)d_out;

  unsigned short* xbf  = (unsigned short*)d_ws;          // 4M shorts
  unsigned short* wqkv = xbf  + (size_t)4 * 1024 * 1024; // 3M
  unsigned short* wobf = wqkv + (size_t)3 * 1024 * 1024; // 1M
  unsigned short* qbf  = wobf + (size_t)1 * 1024 * 1024; // 4M (bh,s,d)
  unsigned short* kbf  = qbf  + (size_t)4 * 1024 * 1024; // 4M (tiled frag-major)
  unsigned short* vbf  = kbf  + (size_t)4 * 1024 * 1024; // 4M (V^T tiled)
  unsigned short* obf  = vbf  + (size_t)4 * 1024 * 1024; // 4M (b,s,h*64+d)

  hipLaunchKernelGGL(cast_kernel, dim3(4096), dim3(256), 0, stream, x, xbf, 1048576);
  hipLaunchKernelGGL(cast_w_kernel, dim3(4096), dim3(256), 0, stream,
                     wq, wk, wv, wo, wqkv, wobf);

  hipLaunchKernelGGL(qkv_gemm_kernel, dim3(24, 32), dim3(256), 0, stream,
                     xbf, wqkv, bq, bk, bv, cp, sp, qbf, kbf, vbf);
  hipLaunchKernelGGL(flash_kernel, dim3(32, 32), dim3(256), 0, stream,
                     qbf, kbf, vbf, obf);
  hipLaunchKernelGGL(oproj_gemm_kernel, dim3(8, 64), dim3(256), 0, stream,
                     obf, wobf, bo, out);
}

// Round 10
// 223.928 us; speedup vs baseline: 1.1125x; 1.0126x over previous
//
#include <hip/hip_runtime.h>
#include <stdint.h>
#include <stddef.h>

// ============================================================================
// MHA block on gfx950, bf16 MFMA pipeline.  B=2,S=2048,D=1024,H=16,hd=64.
// R15: apply the flash recipe (R12-R14: frag-major global layout + direct
// fragment reads + zero barriers) to qkv, the binding 68.7us component.
//  - cast_x/cast_w now write X and Wqkv in frag-major TILED layout:
//    chunk(row,kc) = (row>>4)*128 + kc*16 + (row&15) per (panel[128 rows],
//    ktile[64 k]) -- the exact index expression qkv's old LDS reads used, so
//    fragment reads are byte-identical index math, now against global.
//    Lane l reads chunk base+l -> 1KB/instruction coalesced.
//  - qkv: NO LDS, NO barriers.  16 K-steps of {16 frag loads -> 32 MFMA}.
//    X/W panels are L2-resident (256KB, reused 24x/32x).  2x L2-read dup
//    (wave pairs share panels) = 786MB ~= 17TB/s, under the 34.5 ceiling.
//    launch_bounds(256,4) -> <=128 VGPR -> 4 waves/SIMD; TLP hides L2 lat.
//  - wo stays linear (oproj untouched); flash/oproj = R14 (226.7us best).
// Predictions: qkv 68.7 -> 45-55us (LDS 0, occ ~45%, MfmaUtil ~25%); casts
// +5-10us; total 226.7 -> ~200-210us.
// MFMA layouts (verified m89/m91/m120):
//   A-frag: A[m=lane&15][k=(lane>>4)*8+j]  (16B/lane contiguous)
//   B-frag: B[k=(lane>>4)*8+j][n=lane&15] == row-major read of B^T tile
//   C/D:    col=lane&15, row=(lane>>4)*4+reg
// Tiled layout: addr(panel,kt,L) = ((panel*16+kt)*1024 + L)*8 shorts, with
//   L = chunk(row&127, (k&63)>>3), short idx = k&7.  Inverse: hi=L>>7,
//   kc=(L>>4)&7, lo=L&15 -> row = hi*16+lo.
// ============================================================================

typedef __bf16 bf16x8 __attribute__((ext_vector_type(8)));
typedef float  f32x4  __attribute__((ext_vector_type(4)));

__device__ __forceinline__ unsigned short f2b(float f) {
  union { float f; uint32_t u; } v; v.f = f;
  uint32_t u = v.u;
  return (unsigned short)((u + 0x7FFFu + ((u >> 16) & 1u)) >> 16);  // RNE
}

__device__ __forceinline__ void async16(const void* g, void* l) {
  __builtin_amdgcn_global_load_lds(
      (const __attribute__((address_space(1))) void*)g,
      (__attribute__((address_space(3))) void*)l, 16, 0, 0);
}

// ---------------- cast x f32 -> bf16, frag-major tiled ----------------
// One thread per 8-short chunk.  i = ((panel*16 + kt)*1024 + L); reads 8
// consecutive f32 of row (panel*128 + hi*16 + lo) at k = kt*64 + kc*8.
__global__ void cast_x_tiled_kernel(const float* __restrict__ in,   // [4096][1024]
                                    unsigned short* __restrict__ out) {
  int i = blockIdx.x * blockDim.x + threadIdx.x;   // 0..524287
  const int L  = i & 1023;
  const int kt = (i >> 10) & 15;
  const int pn = i >> 14;                          // 0..31
  const int row = pn * 128 + ((L >> 7) << 4) + (L & 15);
  const int k0  = kt * 64 + ((L >> 4) & 7) * 8;
  const float4* src = (const float4*)(in + (size_t)row * 1024 + k0);
  float4 a = src[0], b = src[1];
  uint4 pk;
  pk.x = (uint32_t)f2b(a.x) | ((uint32_t)f2b(a.y) << 16);
  pk.y = (uint32_t)f2b(a.z) | ((uint32_t)f2b(a.w) << 16);
  pk.z = (uint32_t)f2b(b.x) | ((uint32_t)f2b(b.y) << 16);
  pk.w = (uint32_t)f2b(b.z) | ((uint32_t)f2b(b.w) << 16);
  *(uint4*)(out + (size_t)i * 8) = pk;
}

// ---------------- cast wq/wk/wv f32 -> bf16, frag-major tiled -------------
// mat = i>>17 (0..2); within matrix: 8 panels x 16 ktiles x 1024 chunks.
// Global panel index mat*8+panel == qkv's nblk (0..23).
__global__ void cast_w_tiled_kernel(const float* __restrict__ wq,
                                    const float* __restrict__ wk,
                                    const float* __restrict__ wv,
                                    unsigned short* __restrict__ out) {
  int i = blockIdx.x * blockDim.x + threadIdx.x;   // 0..393215
  const int mat = i >> 17;
  const int rem = i & 131071;
  const int L  = rem & 1023;
  const int kt = (rem >> 10) & 15;
  const int pn = rem >> 14;                        // 0..7
  const float* src = (mat == 0) ? wq : (mat == 1) ? wk : wv;
  const int row = pn * 128 + ((L >> 7) << 4) + (L & 15);
  const int k0  = kt * 64 + ((L >> 4) & 7) * 8;
  const float4* s = (const float4*)(src + (size_t)row * 1024 + k0);
  float4 a = s[0], b = s[1];
  uint4 pk;
  pk.x = (uint32_t)f2b(a.x) | ((uint32_t)f2b(a.y) << 16);
  pk.y = (uint32_t)f2b(a.z) | ((uint32_t)f2b(a.w) << 16);
  pk.z = (uint32_t)f2b(b.x) | ((uint32_t)f2b(b.y) << 16);
  pk.w = (uint32_t)f2b(b.z) | ((uint32_t)f2b(b.w) << 16);
  *(uint4*)(out + (size_t)i * 8) = pk;
}

// ---------------- cast wo f32 -> bf16 (linear, for oproj) ----------------
__global__ void cast_kernel(const float* __restrict__ in,
                            unsigned short* __restrict__ out, int n4) {
  int i = blockIdx.x * blockDim.x + threadIdx.x;
  if (i >= n4) return;
  float4 v = ((const float4*)in)[i];
  ushort4 o;
  o.x = f2b(v.x); o.y = f2b(v.y); o.z = f2b(v.z); o.w = f2b(v.w);
  ((ushort4*)out)[i] = o;
}

// ---------------- fused QKV projection GEMM (+bias, +RoPE on q/k) ----------
// R15: barrier-free, LDS-free.  A (X) and W tiled frag-major; fragments read
// directly from global (1KB/instruction coalesced, L2-resident panels).
// Output layouts (unchanged):
//   q: [bh][2048][64] row-major (RoPE'd)
//   k: tiled frag-major: [bh][st=32][ chunk L = (d>>3)*64 + (s&63) ][8 of d]
//   v: V^T tiled frag-major: [bh][st=32][ chunk L = ((s&63)>>3)*64 + d ][8 of s]
__global__ __launch_bounds__(256, 4) void qkv_gemm_kernel(
    const unsigned short* __restrict__ A,    // x_bf TILED [32 pn][16 kt][1024 L][8]
    const unsigned short* __restrict__ W,    // wqkv TILED [24 pn][16 kt][1024 L][8]
    const float* __restrict__ biasq, const float* __restrict__ biask,
    const float* __restrict__ biasv,
    const float* __restrict__ cp, const float* __restrict__ sp,  // [2048][32]
    unsigned short* __restrict__ qo,
    unsigned short* __restrict__ ko,
    unsigned short* __restrict__ vo)
{
  const int tid  = threadIdx.x;
  const int w    = tid >> 6, l = tid & 63;
  const int lm   = l & 15,  quad = l >> 4;
  const int nblk = blockIdx.x;               // 0..23
  const int m0   = blockIdx.y * 128;
  const int wm   = (w >> 1) * 64, wn = (w & 1) * 64;

  const unsigned short* At = A + (size_t)blockIdx.y * 16 * 8192;  // m-panel
  const unsigned short* Wt = W + (size_t)nblk * 16 * 8192;        // n-panel

  const f32x4 fzero = {0.f, 0.f, 0.f, 0.f};
  f32x4 acc[4][4];
#pragma unroll
  for (int i = 0; i < 4; ++i)
#pragma unroll
    for (int j = 0; j < 4; ++j) acc[i][j] = fzero;

#pragma unroll 1
  for (int t = 0; t < 16; ++t) {
    const unsigned short* Ab = At + (size_t)t * 8192;
    const unsigned short* Wb = Wt + (size_t)t * 8192;
#pragma unroll
    for (int kk = 0; kk < 2; ++kk) {
      bf16x8 af[4], bfc[4];
#pragma unroll
      for (int i = 0; i < 4; ++i)
        af[i] = *(const bf16x8*)(Ab + (size_t)((((w >> 1) * 4 + i) * 128 + kk * 64 + l)) * 8);
#pragma unroll
      for (int j = 0; j < 4; ++j)
        bfc[j] = *(const bf16x8*)(Wb + (size_t)((((w & 1) * 4 + j) * 128 + kk * 64 + l)) * 8);
#pragma unroll
      for (int i = 0; i < 4; ++i)
#pragma unroll
        for (int j = 0; j < 4; ++j)
          acc[i][j] = __builtin_amdgcn_mfma_f32_16x16x32_bf16(af[i], bfc[j], acc[i][j], 0, 0, 0);
    }
  }

  const int which = nblk >> 3;               // 0=q 1=k 2=v
  const int n0    = (nblk & 7) * 128;
  const float* bias = (which == 0) ? biasq : (which == 1) ? biask : biasv;
#pragma unroll
  for (int i = 0; i < 4; ++i) {
#pragma unroll
    for (int j = 0; j < 4; ++j) {
      const int n = n0 + wn + j * 16 + lm;
      const float bval = bias[n];
      const int h = n >> 6, d = n & 63;
      float vals[4];
#pragma unroll
      for (int r = 0; r < 4; ++r) {
        const int m = m0 + wm + i * 16 + quad * 4 + r;
        const int srow = m & 2047;
        float val = acc[i][j][r] + bval;
        if (which != 2) {
          const float c  = cp[srow * 32 + (d >> 1)];
          const float sn = sp[srow * 32 + (d >> 1)];
          const float part = __shfl_xor(val, 1, 64);
          val = (d & 1) ? (part * sn + val * c) : (val * c - part * sn);
        }
        vals[r] = val;
      }
      const int mbase = m0 + wm + i * 16 + quad * 4;   // 4 consecutive s
      const int b = mbase >> 11, s0 = mbase & 2047;
      const int bh = (b << 4) + h;
      if (which == 0) {
#pragma unroll
        for (int r = 0; r < 4; ++r)
          qo[((size_t)bh * 2048 + s0 + r) * 64 + d] = f2b(vals[r]);
      } else if (which == 1) {
        // tiled: base = (bh*32 + s>>6)*4096 + ((d>>3)*64 + (s&63))*8 + (d&7)
#pragma unroll
        for (int r = 0; r < 4; ++r) {
          const int s = s0 + r;
          ko[((size_t)bh * 32 + (s >> 6)) * 4096 +
             (size_t)(((d >> 3) * 64 + (s & 63))) * 8 + (d & 7)] = f2b(vals[r]);
        }
      } else {
        // V^T tiled, 4 consecutive s -> one uint2 (8B) store
        uint32_t w0 = (uint32_t)f2b(vals[0]) | ((uint32_t)f2b(vals[1]) << 16);
        uint32_t w1 = (uint32_t)f2b(vals[2]) | ((uint32_t)f2b(vals[3]) << 16);
        uint2 pk; pk.x = w0; pk.y = w1;
        *(uint2*)(vo + ((size_t)bh * 32 + (s0 >> 6)) * 4096 +
                  (size_t)((((s0 & 63) >> 3) * 64 + d)) * 8 + (s0 & 7)) = pk;
      }
    }
  }
}

// ---------------- flash attention (R14-proven: 16 rows/wave, 4 blk/CU) ----
// grid (bh=32, 32); block 256 thr = 4 waves; block covers 64 q-rows
// (qt*64 .. +63), wave w owns rows qt*64 + w*16 + lm.  Barrier-free; K/V
// direct from global (frag-major, cache-resident).  Mask only on the
// diagonal tile (kt == qt).  T13 defer-max (THR=8) skips rescale.
__global__ __launch_bounds__(256, 4) void flash_kernel(
    const unsigned short* __restrict__ Q,    // [32][2048][64] row-major
    const unsigned short* __restrict__ K,    // tiled frag-major (see qkv)
    const unsigned short* __restrict__ VT,   // V^T tiled frag-major
    unsigned short* __restrict__ O)          // [2][2048][1024]
{
  constexpr int PSTRIDE = 72;                // Ps row stride (shorts)
  __shared__ unsigned short Ps[64 * PSTRIDE];    // 9 KB (only LDS)
  const int tid = threadIdx.x;
  const int w = tid >> 6, l = tid & 63, lm = l & 15, quad = l >> 4;
  const int bh = blockIdx.x, qt = 31 - (int)blockIdx.y;  // heavy first
  const int row0 = qt * 64 + w * 16;         // wave's first q-row

  // Q fragments: lane reads row row0+lm, 8 d at kc*32+quad*8
  bf16x8 aq[2];
#pragma unroll
  for (int kc = 0; kc < 2; ++kc)
    aq[kc] = *(const bf16x8*)(Q + ((size_t)bh * 2048 + row0 + lm) * 64 + kc * 32 + quad * 8);

  const f32x4 fzero = {0.f, 0.f, 0.f, 0.f};
  f32x4 Oacc[4];
#pragma unroll
  for (int jo = 0; jo < 4; ++jo) Oacc[jo] = fzero;
  float m_i = -1e30f, l_i = 0.f;

  const int nkv = qt + 1;

  // ---- unmasked tiles 0 .. qt-1 ----
#pragma unroll 1
  for (int kt = 0; kt < nkv - 1; ++kt) {
    const size_t tbase = ((size_t)bh * 32 + kt) * 4096;
    bf16x8 kf[2][4], vf[2][4];
#pragma unroll
    for (int kc = 0; kc < 2; ++kc)
#pragma unroll
      for (int tb = 0; tb < 4; ++tb) {
        const size_t off = tbase + (size_t)(((kc * 4 + quad) * 64 + tb * 16 + lm)) * 8;
        kf[kc][tb] = *(const bf16x8*)(K + off);
        vf[kc][tb] = *(const bf16x8*)(VT + off);
      }
    // S^T = K * Q^T : Sc[tb] holds t = tb*16+quad*4+r (rows), m = lm (col)
    f32x4 Sc[4];
#pragma unroll
    for (int tb = 0; tb < 4; ++tb) Sc[tb] = fzero;
#pragma unroll
    for (int kc = 0; kc < 2; ++kc)
#pragma unroll
      for (int tb = 0; tb < 4; ++tb)
        Sc[tb] = __builtin_amdgcn_mfma_f32_16x16x32_bf16(kf[kc][tb], aq[kc], Sc[tb], 0, 0, 0);

    float mx = -1e30f;
#pragma unroll
    for (int tb = 0; tb < 4; ++tb)
#pragma unroll
      for (int r = 0; r < 4; ++r) {
        float s = Sc[tb][r] * 0.125f;        // 1/sqrt(64)
        Sc[tb][r] = s;
        mx = fmaxf(mx, s);
      }
    mx = fmaxf(mx, __shfl_xor(mx, 16, 64));
    mx = fmaxf(mx, __shfl_xor(mx, 32, 64));

    // T13 defer-max: skip rescale when all rows grew by <= 8
    const bool skip = (bool)__all(mx - m_i <= 8.0f);
    float alpha = 1.f;
    if (!skip) {
      const float mnew = fmaxf(m_i, mx);
      alpha = __expf(m_i - mnew);
      m_i = mnew;
    }
    const float mref = m_i;

    float ps = 0.f;
#pragma unroll
    for (int tb = 0; tb < 4; ++tb) {
      float p0 = __expf(Sc[tb][0] - mref), p1 = __expf(Sc[tb][1] - mref);
      float p2 = __expf(Sc[tb][2] - mref), p3 = __expf(Sc[tb][3] - mref);
      ps += (p0 + p1) + (p2 + p3);
      uint2 pk;
      pk.x = (uint32_t)f2b(p0) | ((uint32_t)f2b(p1) << 16);
      pk.y = (uint32_t)f2b(p2) | ((uint32_t)f2b(p3) << 16);
      *(uint2*)(Ps + (size_t)(w * 16 + lm) * PSTRIDE + tb * 16 + quad * 4) = pk;
    }
    ps += __shfl_xor(ps, 16, 64);
    ps += __shfl_xor(ps, 32, 64);
    if (skip) {
      l_i += ps;
    } else {
      l_i = l_i * alpha + ps;
      float af4[4];
#pragma unroll
      for (int r = 0; r < 4; ++r) af4[r] = __shfl(alpha, quad * 4 + r, 64);
#pragma unroll
      for (int jo = 0; jo < 4; ++jo)
#pragma unroll
        for (int r = 0; r < 4; ++r) Oacc[jo][r] *= af4[r];
    }

    // O += P V
#pragma unroll
    for (int kc = 0; kc < 2; ++kc) {
      bf16x8 ap = *(const bf16x8*)(Ps + (size_t)(w * 16 + lm) * PSTRIDE + kc * 32 + quad * 8);
#pragma unroll
      for (int jo = 0; jo < 4; ++jo)
        Oacc[jo] = __builtin_amdgcn_mfma_f32_16x16x32_bf16(ap, vf[kc][jo], Oacc[jo], 0, 0, 0);
    }
  }

  // ---- diagonal (masked) tile kt = qt ----
  {
    const size_t tbase = ((size_t)bh * 32 + qt) * 4096;
    bf16x8 kf[2][4], vf[2][4];
#pragma unroll
    for (int kc = 0; kc < 2; ++kc)
#pragma unroll
      for (int tb = 0; tb < 4; ++tb) {
        const size_t off = tbase + (size_t)(((kc * 4 + quad) * 64 + tb * 16 + lm)) * 8;
        kf[kc][tb] = *(const bf16x8*)(K + off);
        vf[kc][tb] = *(const bf16x8*)(VT + off);
      }
    f32x4 Sc[4];
#pragma unroll
    for (int tb = 0; tb < 4; ++tb) Sc[tb] = fzero;
#pragma unroll
    for (int kc = 0; kc < 2; ++kc)
#pragma unroll
      for (int tb = 0; tb < 4; ++tb)
        Sc[tb] = __builtin_amdgcn_mfma_f32_16x16x32_bf16(kf[kc][tb], aq[kc], Sc[tb], 0, 0, 0);

    const int mrel = w * 16 + lm;            // mask t-index > mrel
    float mx = -1e30f;
#pragma unroll
    for (int tb = 0; tb < 4; ++tb)
#pragma unroll
      for (int r = 0; r < 4; ++r) {
        float s = Sc[tb][r] * 0.125f;
        if (tb * 16 + quad * 4 + r > mrel) s = -1e30f;
        Sc[tb][r] = s;
        mx = fmaxf(mx, s);
      }
    mx = fmaxf(mx, __shfl_xor(mx, 16, 64));
    mx = fmaxf(mx, __shfl_xor(mx, 32, 64));
    const float mnew  = fmaxf(m_i, mx);
    const float alpha = __expf(m_i - mnew);
    m_i = mnew;

    float ps = 0.f;
#pragma unroll
    for (int tb = 0; tb < 4; ++tb) {
      float p0 = __expf(Sc[tb][0] - mnew), p1 = __expf(Sc[tb][1] - mnew);
      float p2 = __expf(Sc[tb][2] - mnew), p3 = __expf(Sc[tb][3] - mnew);
      ps += (p0 + p1) + (p2 + p3);
      uint2 pk;
      pk.x = (uint32_t)f2b(p0) | ((uint32_t)f2b(p1) << 16);
      pk.y = (uint32_t)f2b(p2) | ((uint32_t)f2b(p3) << 16);
      *(uint2*)(Ps + (size_t)(w * 16 + lm) * PSTRIDE + tb * 16 + quad * 4) = pk;
    }
    ps += __shfl_xor(ps, 16, 64);
    ps += __shfl_xor(ps, 32, 64);
    l_i = l_i * alpha + ps;

    float af4[4];
#pragma unroll
    for (int r = 0; r < 4; ++r) af4[r] = __shfl(alpha, quad * 4 + r, 64);
#pragma unroll
    for (int jo = 0; jo < 4; ++jo)
#pragma unroll
      for (int r = 0; r < 4; ++r) Oacc[jo][r] *= af4[r];

#pragma unroll
    for (int kc = 0; kc < 2; ++kc) {
      bf16x8 ap = *(const bf16x8*)(Ps + (size_t)(w * 16 + lm) * PSTRIDE + kc * 32 + quad * 8);
#pragma unroll
      for (int jo = 0; jo < 4; ++jo)
        Oacc[jo] = __builtin_amdgcn_mfma_f32_16x16x32_bf16(ap, vf[kc][jo], Oacc[jo], 0, 0, 0);
    }
  }

  // epilogue: normalize, write o_bf (b, s, h*64+d)
  float lf[4];
#pragma unroll
  for (int r = 0; r < 4; ++r) lf[r] = 1.0f / __shfl(l_i, quad * 4 + r, 64);
  const int b = bh >> 4, h = bh & 15;
#pragma unroll
  for (int jo = 0; jo < 4; ++jo)
#pragma unroll
    for (int r = 0; r < 4; ++r) {
      const int s   = row0 + quad * 4 + r;
      const int col = h * 64 + jo * 16 + lm;
      O[((size_t)b * 2048 + s) * 1024 + col] = f2b(Oacc[jo][r] * lf[r]);
    }
}

// ---------------- output projection GEMM (R5-proven version) ----------------
// out[4096,1024] = Obf[4096,1024] @ Wo[1024,1024]^T + bias (fp32 out).
// 64x128 tiles, BK=64, 512 blocks (2/CU).  Wave w covers cols w*32..w*32+31.
__global__ __launch_bounds__(256) void oproj_gemm_kernel(
    const unsigned short* __restrict__ A,    // o_bf [4096][1024]
    const unsigned short* __restrict__ W,    // wo_bf [1024][1024]
    const float* __restrict__ bias,
    float* __restrict__ out)
{
  __shared__ unsigned short As[64 * 64];     // 8 KB
  __shared__ unsigned short Bs[128 * 64];    // 16 KB
  const int tid = threadIdx.x;
  const int w = tid >> 6, l = tid & 63;
  const int lm = l & 15, quad = l >> 4;
  const int m0 = blockIdx.y * 64;
  const int n0 = blockIdx.x * 128;

  const f32x4 fzero = {0.f, 0.f, 0.f, 0.f};
  f32x4 acc[4][2];
#pragma unroll
  for (int i = 0; i < 4; ++i)
#pragma unroll
    for (int j = 0; j < 2; ++j) acc[i][j] = fzero;

  for (int k0 = 0; k0 < 1024; k0 += 64) {
    __syncthreads();
    // A: 64 rows x 8 kc = 512 chunks; 2 per thread
#pragma unroll
    for (int q = 0; q < 2; ++q) {
      const int row = w * 16 + lm;
      const int kc  = quad + 4 * q;
      async16(A + (size_t)(m0 + row) * 1024 + k0 + kc * 8,
              As + ((size_t)w * 128 + 64 * q) * 8);
    }
    // B: 128 rows x 8 kc = 1024 chunks; 4 per thread
#pragma unroll
    for (int q = 0; q < 4; ++q) {
      const int row = w * 16 + lm + (q & 1) * 64;
      const int kc  = quad + 4 * (q >> 1);
      async16(W + (size_t)(n0 + row) * 1024 + k0 + kc * 8,
              Bs + ((size_t)(w + 4 * (q & 1)) * 128 + 64 * (q >> 1)) * 8);
    }
    __syncthreads();
#pragma unroll
    for (int kk = 0; kk < 2; ++kk) {
      bf16x8 af[4], bfc[2];
#pragma unroll
      for (int i = 0; i < 4; ++i)
        af[i] = *(const bf16x8*)(As + (size_t)((i * 128 + kk * 64 + l)) * 8);
#pragma unroll
      for (int j = 0; j < 2; ++j)
        bfc[j] = *(const bf16x8*)(Bs + (size_t)(((w * 2 + j) * 128 + kk * 64 + l)) * 8);
#pragma unroll
      for (int i = 0; i < 4; ++i)
#pragma unroll
        for (int j = 0; j < 2; ++j)
          acc[i][j] = __builtin_amdgcn_mfma_f32_16x16x32_bf16(af[i], bfc[j], acc[i][j], 0, 0, 0);
    }
  }

#pragma unroll
  for (int i = 0; i < 4; ++i) {
#pragma unroll
    for (int j = 0; j < 2; ++j) {
      const int n = n0 + w * 32 + j * 16 + lm;
      const float bval = bias[n];
#pragma unroll
      for (int r = 0; r < 4; ++r) {
        const int m = m0 + i * 16 + quad * 4 + r;
        out[(size_t)m * 1024 + n] = acc[i][j][r] + bval;
      }
    }
  }
}

// ---------------- host launch ----------------
extern "C" void kernel_launch(void* const* d_in, const int* in_sizes, int n_in,
                              void* d_out, int out_size, void* d_ws, size_t ws_size,
                              hipStream_t stream) {
  (void)in_sizes; (void)n_in; (void)out_size; (void)ws_size;
  const float* x  = (const float*)d_in[0];
  const float* cp = (const float*)d_in[1];
  const float* sp = (const float*)d_in[2];
  const float* wq = (const float*)d_in[3];
  const float* bq = (const float*)d_in[4];
  const float* wk = (const float*)d_in[5];
  const float* bk = (const float*)d_in[6];
  const float* wv = (const float*)d_in[7];
  const float* bv = (const float*)d_in[8];
  const float* wo = (const float*)d_in[9];
  const float* bo = (const float*)d_in[10];
  float* out = (float*)d_out;

  unsigned short* xbf  = (unsigned short*)d_ws;          // 4M shorts (tiled)
  unsigned short* wqkv = xbf  + (size_t)4 * 1024 * 1024; // 3M (tiled)
  unsigned short* wobf = wqkv + (size_t)3 * 1024 * 1024; // 1M (linear)
  unsigned short* qbf  = wobf + (size_t)1 * 1024 * 1024; // 4M (bh,s,d)
  unsigned short* kbf  = qbf  + (size_t)4 * 1024 * 1024; // 4M (tiled frag-major)
  unsigned short* vbf  = kbf  + (size_t)4 * 1024 * 1024; // 4M (V^T tiled)
  unsigned short* obf  = vbf  + (size_t)4 * 1024 * 1024; // 4M (b,s,h*64+d)

  hipLaunchKernelGGL(cast_x_tiled_kernel, dim3(2048), dim3(256), 0, stream, x, xbf);
  hipLaunchKernelGGL(cast_w_tiled_kernel, dim3(1536), dim3(256), 0, stream,
                     wq, wk, wv, wqkv);
  hipLaunchKernelGGL(cast_kernel, dim3(1024), dim3(256), 0, stream, wo, wobf, 262144);

  hipLaunchKernelGGL(qkv_gemm_kernel, dim3(24, 32), dim3(256), 0, stream,
                     xbf, wqkv, bq, bk, bv, cp, sp, qbf, kbf, vbf);
  hipLaunchKernelGGL(flash_kernel, dim3(32, 32), dim3(256), 0, stream,
                     qbf, kbf, vbf, obf);
  hipLaunchKernelGGL(oproj_gemm_kernel, dim3(8, 64), dim3(256), 0, stream,
                     obf, wobf, bo, out);
}

// Round 11
// 209.768 us; speedup vs baseline: 1.1876x; 1.0675x over previous
//
#include <hip/hip_runtime.h>
#include <stdint.h>
#include <stddef.h>

// ============================================================================
// MHA block on gfx950, bf16 MFMA pipeline.  B=2,S=2048,D=1024,H=16,hd=64.
// R16: qkv cross-tile register prefetch (R13-flash recipe ported).
//  - R15 post-mortem: qkv 64us, LDS 0, VGPR 52, MfmaUtil 15%, occ 28%
//    (grid-limited 3 blk/CU).  786MB @ 12.3TB/s from L2/L3 -- not a wall
//    (flash sustained ~18TB/s same path) -> per-tile load->MFMA serialization
//    is the cost.  Fix: ping-pong two 8-frag register sets (pA/pB, qA/qB);
//    loads of half t.kk1 issue while MFMAs of t.kk0 drain, next tile's kk0
//    while kk1 drains.  Macro-form, plain arrays, full unroll (R13 proved
//    no scratch).  launch_bounds(256,3) -> VGPR cap ~168 (est ~150);
//    occupancy unaffected (grid-limited anyway).
//  - flash / oproj / casts: byte-identical to R15 (223.9us best).
// Predictions: qkv 64 -> 45-52us (MfmaUtil ~23%, VGPR ~150, WRITE stays
// 24.6MB); total 224 -> ~205-212us.
// MFMA layouts (verified m89/m91/m120):
//   A-frag: A[m=lane&15][k=(lane>>4)*8+j]  (16B/lane contiguous)
//   B-frag: B[k=(lane>>4)*8+j][n=lane&15] == row-major read of B^T tile
//   C/D:    col=lane&15, row=(lane>>4)*4+reg
// Tiled layout: addr(panel,kt,L) = ((panel*16+kt)*1024 + L)*8 shorts, with
//   L(row,kc) = (row>>4)*128 + (kc>>2)*64 + (kc&3)*16 + (row&15).
// ============================================================================

typedef __bf16 bf16x8 __attribute__((ext_vector_type(8)));
typedef float  f32x4  __attribute__((ext_vector_type(4)));

__device__ __forceinline__ unsigned short f2b(float f) {
  union { float f; uint32_t u; } v; v.f = f;
  uint32_t u = v.u;
  return (unsigned short)((u + 0x7FFFu + ((u >> 16) & 1u)) >> 16);  // RNE
}

__device__ __forceinline__ void async16(const void* g, void* l) {
  __builtin_amdgcn_global_load_lds(
      (const __attribute__((address_space(1))) void*)g,
      (__attribute__((address_space(3))) void*)l, 16, 0, 0);
}

// ---------------- cast x f32 -> bf16, frag-major tiled ----------------
__global__ void cast_x_tiled_kernel(const float* __restrict__ in,   // [4096][1024]
                                    unsigned short* __restrict__ out) {
  int i = blockIdx.x * blockDim.x + threadIdx.x;   // 0..524287
  const int L  = i & 1023;
  const int kt = (i >> 10) & 15;
  const int pn = i >> 14;                          // 0..31
  const int row = pn * 128 + ((L >> 7) << 4) + (L & 15);
  const int k0  = kt * 64 + ((L >> 4) & 7) * 8;
  const float4* src = (const float4*)(in + (size_t)row * 1024 + k0);
  float4 a = src[0], b = src[1];
  uint4 pk;
  pk.x = (uint32_t)f2b(a.x) | ((uint32_t)f2b(a.y) << 16);
  pk.y = (uint32_t)f2b(a.z) | ((uint32_t)f2b(a.w) << 16);
  pk.z = (uint32_t)f2b(b.x) | ((uint32_t)f2b(b.y) << 16);
  pk.w = (uint32_t)f2b(b.z) | ((uint32_t)f2b(b.w) << 16);
  *(uint4*)(out + (size_t)i * 8) = pk;
}

// ---------------- cast wq/wk/wv f32 -> bf16, frag-major tiled -------------
__global__ void cast_w_tiled_kernel(const float* __restrict__ wq,
                                    const float* __restrict__ wk,
                                    const float* __restrict__ wv,
                                    unsigned short* __restrict__ out) {
  int i = blockIdx.x * blockDim.x + threadIdx.x;   // 0..393215
  const int mat = i >> 17;
  const int rem = i & 131071;
  const int L  = rem & 1023;
  const int kt = (rem >> 10) & 15;
  const int pn = rem >> 14;                        // 0..7
  const float* src = (mat == 0) ? wq : (mat == 1) ? wk : wv;
  const int row = pn * 128 + ((L >> 7) << 4) + (L & 15);
  const int k0  = kt * 64 + ((L >> 4) & 7) * 8;
  const float4* s = (const float4*)(src + (size_t)row * 1024 + k0);
  float4 a = s[0], b = s[1];
  uint4 pk;
  pk.x = (uint32_t)f2b(a.x) | ((uint32_t)f2b(a.y) << 16);
  pk.y = (uint32_t)f2b(a.z) | ((uint32_t)f2b(a.w) << 16);
  pk.z = (uint32_t)f2b(b.x) | ((uint32_t)f2b(b.y) << 16);
  pk.w = (uint32_t)f2b(b.z) | ((uint32_t)f2b(b.w) << 16);
  *(uint4*)(out + (size_t)i * 8) = pk;
}

// ---------------- cast wo f32 -> bf16 (linear, for oproj) ----------------
__global__ void cast_kernel(const float* __restrict__ in,
                            unsigned short* __restrict__ out, int n4) {
  int i = blockIdx.x * blockDim.x + threadIdx.x;
  if (i >= n4) return;
  float4 v = ((const float4*)in)[i];
  ushort4 o;
  o.x = f2b(v.x); o.y = f2b(v.y); o.z = f2b(v.z); o.w = f2b(v.w);
  ((ushort4*)out)[i] = o;
}

// ---------------- fused QKV projection GEMM (+bias, +RoPE on q/k) ----------
// R16: LDS-free, barrier-free, cross-half register-prefetch pipeline.
// Output layouts (unchanged):
//   q: [bh][2048][64] row-major (RoPE'd)
//   k: tiled frag-major: [bh][st=32][ chunk L = (d>>3)*64 + (s&63) ][8 of d]
//   v: V^T tiled frag-major: [bh][st=32][ chunk L = ((s&63)>>3)*64 + d ][8 of s]
__global__ __launch_bounds__(256, 3) void qkv_gemm_kernel(
    const unsigned short* __restrict__ A,    // x_bf TILED [32 pn][16 kt][1024 L][8]
    const unsigned short* __restrict__ W,    // wqkv TILED [24 pn][16 kt][1024 L][8]
    const float* __restrict__ biasq, const float* __restrict__ biask,
    const float* __restrict__ biasv,
    const float* __restrict__ cp, const float* __restrict__ sp,  // [2048][32]
    unsigned short* __restrict__ qo,
    unsigned short* __restrict__ ko,
    unsigned short* __restrict__ vo)
{
  const int tid  = threadIdx.x;
  const int w    = tid >> 6, l = tid & 63;
  const int lm   = l & 15,  quad = l >> 4;
  const int nblk = blockIdx.x;               // 0..23
  const int m0   = blockIdx.y * 128;
  const int wm   = (w >> 1) * 64, wn = (w & 1) * 64;

  const unsigned short* At = A + (size_t)blockIdx.y * 16 * 8192;  // m-panel
  const unsigned short* Wt = W + (size_t)nblk * 16 * 8192;        // n-panel

  const f32x4 fzero = {0.f, 0.f, 0.f, 0.f};
  f32x4 acc[4][4];
#pragma unroll
  for (int i = 0; i < 4; ++i)
#pragma unroll
    for (int j = 0; j < 4; ++j) acc[i][j] = fzero;

  bf16x8 pA[4], pB[4], qA[4], qB[4];         // two 8-frag ping-pong sets

#define QKV_LOADH(DA, DB, T, KK)                                              \
  {                                                                           \
    const unsigned short* Ab_ = At + (size_t)(T) * 8192;                      \
    const unsigned short* Wb_ = Wt + (size_t)(T) * 8192;                      \
    _Pragma("unroll")                                                         \
    for (int i = 0; i < 4; ++i)                                               \
      DA[i] = *(const bf16x8*)(Ab_ +                                          \
          (size_t)((((w >> 1) * 4 + i) * 128 + (KK) * 64 + l)) * 8);          \
    _Pragma("unroll")                                                         \
    for (int j = 0; j < 4; ++j)                                               \
      DB[j] = *(const bf16x8*)(Wb_ +                                          \
          (size_t)((((w & 1) * 4 + j) * 128 + (KK) * 64 + l)) * 8);           \
  }

#define QKV_MFMAH(SA, SB)                                                     \
  _Pragma("unroll")                                                           \
  for (int i = 0; i < 4; ++i)                                                 \
    _Pragma("unroll")                                                         \
    for (int j = 0; j < 4; ++j)                                               \
      acc[i][j] = __builtin_amdgcn_mfma_f32_16x16x32_bf16(SA[i], SB[j],       \
                                                          acc[i][j], 0, 0, 0);

  QKV_LOADH(pA, pB, 0, 0);                   // prologue: tile 0, half kk=0
#pragma unroll 1
  for (int t = 0; t < 16; ++t) {
    QKV_LOADH(qA, qB, t, 1);                 // issue kk=1 loads...
    QKV_MFMAH(pA, pB);                       // ...under kk=0 MFMAs
    if (t < 15) QKV_LOADH(pA, pB, t + 1, 0); // issue next tile's kk=0...
    QKV_MFMAH(qA, qB);                       // ...under kk=1 MFMAs
  }
#undef QKV_LOADH
#undef QKV_MFMAH

  const int which = nblk >> 3;               // 0=q 1=k 2=v
  const int n0    = (nblk & 7) * 128;
  const float* bias = (which == 0) ? biasq : (which == 1) ? biask : biasv;
#pragma unroll
  for (int i = 0; i < 4; ++i) {
#pragma unroll
    for (int j = 0; j < 4; ++j) {
      const int n = n0 + wn + j * 16 + lm;
      const float bval = bias[n];
      const int h = n >> 6, d = n & 63;
      float vals[4];
#pragma unroll
      for (int r = 0; r < 4; ++r) {
        const int m = m0 + wm + i * 16 + quad * 4 + r;
        const int srow = m & 2047;
        float val = acc[i][j][r] + bval;
        if (which != 2) {
          const float c  = cp[srow * 32 + (d >> 1)];
          const float sn = sp[srow * 32 + (d >> 1)];
          const float part = __shfl_xor(val, 1, 64);
          val = (d & 1) ? (part * sn + val * c) : (val * c - part * sn);
        }
        vals[r] = val;
      }
      const int mbase = m0 + wm + i * 16 + quad * 4;   // 4 consecutive s
      const int b = mbase >> 11, s0 = mbase & 2047;
      const int bh = (b << 4) + h;
      if (which == 0) {
#pragma unroll
        for (int r = 0; r < 4; ++r)
          qo[((size_t)bh * 2048 + s0 + r) * 64 + d] = f2b(vals[r]);
      } else if (which == 1) {
        // tiled: base = (bh*32 + s>>6)*4096 + ((d>>3)*64 + (s&63))*8 + (d&7)
#pragma unroll
        for (int r = 0; r < 4; ++r) {
          const int s = s0 + r;
          ko[((size_t)bh * 32 + (s >> 6)) * 4096 +
             (size_t)(((d >> 3) * 64 + (s & 63))) * 8 + (d & 7)] = f2b(vals[r]);
        }
      } else {
        // V^T tiled, 4 consecutive s -> one uint2 (8B) store
        uint32_t w0 = (uint32_t)f2b(vals[0]) | ((uint32_t)f2b(vals[1]) << 16);
        uint32_t w1 = (uint32_t)f2b(vals[2]) | ((uint32_t)f2b(vals[3]) << 16);
        uint2 pk; pk.x = w0; pk.y = w1;
        *(uint2*)(vo + ((size_t)bh * 32 + (s0 >> 6)) * 4096 +
                  (size_t)((((s0 & 63) >> 3) * 64 + d)) * 8 + (s0 & 7)) = pk;
      }
    }
  }
}

// ---------------- flash attention (R14/R15-proven) ------------------------
// grid (bh=32, 32); block 256 thr = 4 waves; block covers 64 q-rows
// (qt*64 .. +63), wave w owns rows qt*64 + w*16 + lm.  Barrier-free; K/V
// direct from global (frag-major, cache-resident).  Mask only on the
// diagonal tile (kt == qt).  T13 defer-max (THR=8) skips rescale.
__global__ __launch_bounds__(256, 4) void flash_kernel(
    const unsigned short* __restrict__ Q,    // [32][2048][64] row-major
    const unsigned short* __restrict__ K,    // tiled frag-major (see qkv)
    const unsigned short* __restrict__ VT,   // V^T tiled frag-major
    unsigned short* __restrict__ O)          // [2][2048][1024]
{
  constexpr int PSTRIDE = 72;                // Ps row stride (shorts)
  __shared__ unsigned short Ps[64 * PSTRIDE];    // 9 KB (only LDS)
  const int tid = threadIdx.x;
  const int w = tid >> 6, l = tid & 63, lm = l & 15, quad = l >> 4;
  const int bh = blockIdx.x, qt = 31 - (int)blockIdx.y;  // heavy first
  const int row0 = qt * 64 + w * 16;         // wave's first q-row

  // Q fragments: lane reads row row0+lm, 8 d at kc*32+quad*8
  bf16x8 aq[2];
#pragma unroll
  for (int kc = 0; kc < 2; ++kc)
    aq[kc] = *(const bf16x8*)(Q + ((size_t)bh * 2048 + row0 + lm) * 64 + kc * 32 + quad * 8);

  const f32x4 fzero = {0.f, 0.f, 0.f, 0.f};
  f32x4 Oacc[4];
#pragma unroll
  for (int jo = 0; jo < 4; ++jo) Oacc[jo] = fzero;
  float m_i = -1e30f, l_i = 0.f;

  const int nkv = qt + 1;

  // ---- unmasked tiles 0 .. qt-1 ----
#pragma unroll 1
  for (int kt = 0; kt < nkv - 1; ++kt) {
    const size_t tbase = ((size_t)bh * 32 + kt) * 4096;
    bf16x8 kf[2][4], vf[2][4];
#pragma unroll
    for (int kc = 0; kc < 2; ++kc)
#pragma unroll
      for (int tb = 0; tb < 4; ++tb) {
        const size_t off = tbase + (size_t)(((kc * 4 + quad) * 64 + tb * 16 + lm)) * 8;
        kf[kc][tb] = *(const bf16x8*)(K + off);
        vf[kc][tb] = *(const bf16x8*)(VT + off);
      }
    // S^T = K * Q^T : Sc[tb] holds t = tb*16+quad*4+r (rows), m = lm (col)
    f32x4 Sc[4];
#pragma unroll
    for (int tb = 0; tb < 4; ++tb) Sc[tb] = fzero;
#pragma unroll
    for (int kc = 0; kc < 2; ++kc)
#pragma unroll
      for (int tb = 0; tb < 4; ++tb)
        Sc[tb] = __builtin_amdgcn_mfma_f32_16x16x32_bf16(kf[kc][tb], aq[kc], Sc[tb], 0, 0, 0);

    float mx = -1e30f;
#pragma unroll
    for (int tb = 0; tb < 4; ++tb)
#pragma unroll
      for (int r = 0; r < 4; ++r) {
        float s = Sc[tb][r] * 0.125f;        // 1/sqrt(64)
        Sc[tb][r] = s;
        mx = fmaxf(mx, s);
      }
    mx = fmaxf(mx, __shfl_xor(mx, 16, 64));
    mx = fmaxf(mx, __shfl_xor(mx, 32, 64));

    // T13 defer-max: skip rescale when all rows grew by <= 8
    const bool skip = (bool)__all(mx - m_i <= 8.0f);
    float alpha = 1.f;
    if (!skip) {
      const float mnew = fmaxf(m_i, mx);
      alpha = __expf(m_i - mnew);
      m_i = mnew;
    }
    const float mref = m_i;

    float ps = 0.f;
#pragma unroll
    for (int tb = 0; tb < 4; ++tb) {
      float p0 = __expf(Sc[tb][0] - mref), p1 = __expf(Sc[tb][1] - mref);
      float p2 = __expf(Sc[tb][2] - mref), p3 = __expf(Sc[tb][3] - mref);
      ps += (p0 + p1) + (p2 + p3);
      uint2 pk;
      pk.x = (uint32_t)f2b(p0) | ((uint32_t)f2b(p1) << 16);
      pk.y = (uint32_t)f2b(p2) | ((uint32_t)f2b(p3) << 16);
      *(uint2*)(Ps + (size_t)(w * 16 + lm) * PSTRIDE + tb * 16 + quad * 4) = pk;
    }
    ps += __shfl_xor(ps, 16, 64);
    ps += __shfl_xor(ps, 32, 64);
    if (skip) {
      l_i += ps;
    } else {
      l_i = l_i * alpha + ps;
      float af4[4];
#pragma unroll
      for (int r = 0; r < 4; ++r) af4[r] = __shfl(alpha, quad * 4 + r, 64);
#pragma unroll
      for (int jo = 0; jo < 4; ++jo)
#pragma unroll
        for (int r = 0; r < 4; ++r) Oacc[jo][r] *= af4[r];
    }

    // O += P V
#pragma unroll
    for (int kc = 0; kc < 2; ++kc) {
      bf16x8 ap = *(const bf16x8*)(Ps + (size_t)(w * 16 + lm) * PSTRIDE + kc * 32 + quad * 8);
#pragma unroll
      for (int jo = 0; jo < 4; ++jo)
        Oacc[jo] = __builtin_amdgcn_mfma_f32_16x16x32_bf16(ap, vf[kc][jo], Oacc[jo], 0, 0, 0);
    }
  }

  // ---- diagonal (masked) tile kt = qt ----
  {
    const size_t tbase = ((size_t)bh * 32 + qt) * 4096;
    bf16x8 kf[2][4], vf[2][4];
#pragma unroll
    for (int kc = 0; kc < 2; ++kc)
#pragma unroll
      for (int tb = 0; tb < 4; ++tb) {
        const size_t off = tbase + (size_t)(((kc * 4 + quad) * 64 + tb * 16 + lm)) * 8;
        kf[kc][tb] = *(const bf16x8*)(K + off);
        vf[kc][tb] = *(const bf16x8*)(VT + off);
      }
    f32x4 Sc[4];
#pragma unroll
    for (int tb = 0; tb < 4; ++tb) Sc[tb] = fzero;
#pragma unroll
    for (int kc = 0; kc < 2; ++kc)
#pragma unroll
      for (int tb = 0; tb < 4; ++tb)
        Sc[tb] = __builtin_amdgcn_mfma_f32_16x16x32_bf16(kf[kc][tb], aq[kc], Sc[tb], 0, 0, 0);

    const int mrel = w * 16 + lm;            // mask t-index > mrel
    float mx = -1e30f;
#pragma unroll
    for (int tb = 0; tb < 4; ++tb)
#pragma unroll
      for (int r = 0; r < 4; ++r) {
        float s = Sc[tb][r] * 0.125f;
        if (tb * 16 + quad * 4 + r > mrel) s = -1e30f;
        Sc[tb][r] = s;
        mx = fmaxf(mx, s);
      }
    mx = fmaxf(mx, __shfl_xor(mx, 16, 64));
    mx = fmaxf(mx, __shfl_xor(mx, 32, 64));
    const float mnew  = fmaxf(m_i, mx);
    const float alpha = __expf(m_i - mnew);
    m_i = mnew;

    float ps = 0.f;
#pragma unroll
    for (int tb = 0; tb < 4; ++tb) {
      float p0 = __expf(Sc[tb][0] - mnew), p1 = __expf(Sc[tb][1] - mnew);
      float p2 = __expf(Sc[tb][2] - mnew), p3 = __expf(Sc[tb][3] - mnew);
      ps += (p0 + p1) + (p2 + p3);
      uint2 pk;
      pk.x = (uint32_t)f2b(p0) | ((uint32_t)f2b(p1) << 16);
      pk.y = (uint32_t)f2b(p2) | ((uint32_t)f2b(p3) << 16);
      *(uint2*)(Ps + (size_t)(w * 16 + lm) * PSTRIDE + tb * 16 + quad * 4) = pk;
    }
    ps += __shfl_xor(ps, 16, 64);
    ps += __shfl_xor(ps, 32, 64);
    l_i = l_i * alpha + ps;

    float af4[4];
#pragma unroll
    for (int r = 0; r < 4; ++r) af4[r] = __shfl(alpha, quad * 4 + r, 64);
#pragma unroll
    for (int jo = 0; jo < 4; ++jo)
#pragma unroll
      for (int r = 0; r < 4; ++r) Oacc[jo][r] *= af4[r];

#pragma unroll
    for (int kc = 0; kc < 2; ++kc) {
      bf16x8 ap = *(const bf16x8*)(Ps + (size_t)(w * 16 + lm) * PSTRIDE + kc * 32 + quad * 8);
#pragma unroll
      for (int jo = 0; jo < 4; ++jo)
        Oacc[jo] = __builtin_amdgcn_mfma_f32_16x16x32_bf16(ap, vf[kc][jo], Oacc[jo], 0, 0, 0);
    }
  }

  // epilogue: normalize, write o_bf (b, s, h*64+d)
  float lf[4];
#pragma unroll
  for (int r = 0; r < 4; ++r) lf[r] = 1.0f / __shfl(l_i, quad * 4 + r, 64);
  const int b = bh >> 4, h = bh & 15;
#pragma unroll
  for (int jo = 0; jo < 4; ++jo)
#pragma unroll
    for (int r = 0; r < 4; ++r) {
      const int s   = row0 + quad * 4 + r;
      const int col = h * 64 + jo * 16 + lm;
      O[((size_t)b * 2048 + s) * 1024 + col] = f2b(Oacc[jo][r] * lf[r]);
    }
}

// ---------------- output projection GEMM (R5-proven version) ----------------
// out[4096,1024] = Obf[4096,1024] @ Wo[1024,1024]^T + bias (fp32 out).
// 64x128 tiles, BK=64, 512 blocks (2/CU).  Wave w covers cols w*32..w*32+31.
__global__ __launch_bounds__(256) void oproj_gemm_kernel(
    const unsigned short* __restrict__ A,    // o_bf [4096][1024]
    const unsigned short* __restrict__ W,    // wo_bf [1024][1024]
    const float* __restrict__ bias,
    float* __restrict__ out)
{
  __shared__ unsigned short As[64 * 64];     // 8 KB
  __shared__ unsigned short Bs[128 * 64];    // 16 KB
  const int tid = threadIdx.x;
  const int w = tid >> 6, l = tid & 63;
  const int lm = l & 15, quad = l >> 4;
  const int m0 = blockIdx.y * 64;
  const int n0 = blockIdx.x * 128;

  const f32x4 fzero = {0.f, 0.f, 0.f, 0.f};
  f32x4 acc[4][2];
#pragma unroll
  for (int i = 0; i < 4; ++i)
#pragma unroll
    for (int j = 0; j < 2; ++j) acc[i][j] = fzero;

  for (int k0 = 0; k0 < 1024; k0 += 64) {
    __syncthreads();
    // A: 64 rows x 8 kc = 512 chunks; 2 per thread
#pragma unroll
    for (int q = 0; q < 2; ++q) {
      const int row = w * 16 + lm;
      const int kc  = quad + 4 * q;
      async16(A + (size_t)(m0 + row) * 1024 + k0 + kc * 8,
              As + ((size_t)w * 128 + 64 * q) * 8);
    }
    // B: 128 rows x 8 kc = 1024 chunks; 4 per thread
#pragma unroll
    for (int q = 0; q < 4; ++q) {
      const int row = w * 16 + lm + (q & 1) * 64;
      const int kc  = quad + 4 * (q >> 1);
      async16(W + (size_t)(n0 + row) * 1024 + k0 + kc * 8,
              Bs + ((size_t)(w + 4 * (q & 1)) * 128 + 64 * (q >> 1)) * 8);
    }
    __syncthreads();
#pragma unroll
    for (int kk = 0; kk < 2; ++kk) {
      bf16x8 af[4], bfc[2];
#pragma unroll
      for (int i = 0; i < 4; ++i)
        af[i] = *(const bf16x8*)(As + (size_t)((i * 128 + kk * 64 + l)) * 8);
#pragma unroll
      for (int j = 0; j < 2; ++j)
        bfc[j] = *(const bf16x8*)(Bs + (size_t)(((w * 2 + j) * 128 + kk * 64 + l)) * 8);
#pragma unroll
      for (int i = 0; i < 4; ++i)
#pragma unroll
        for (int j = 0; j < 2; ++j)
          acc[i][j] = __builtin_amdgcn_mfma_f32_16x16x32_bf16(af[i], bfc[j], acc[i][j], 0, 0, 0);
    }
  }

#pragma unroll
  for (int i = 0; i < 4; ++i) {
#pragma unroll
    for (int j = 0; j < 2; ++j) {
      const int n = n0 + w * 32 + j * 16 + lm;
      const float bval = bias[n];
#pragma unroll
      for (int r = 0; r < 4; ++r) {
        const int m = m0 + i * 16 + quad * 4 + r;
        out[(size_t)m * 1024 + n] = acc[i][j][r] + bval;
      }
    }
  }
}

// ---------------- host launch ----------------
extern "C" void kernel_launch(void* const* d_in, const int* in_sizes, int n_in,
                              void* d_out, int out_size, void* d_ws, size_t ws_size,
                              hipStream_t stream) {
  (void)in_sizes; (void)n_in; (void)out_size; (void)ws_size;
  const float* x  = (const float*)d_in[0];
  const float* cp = (const float*)d_in[1];
  const float* sp = (const float*)d_in[2];
  const float* wq = (const float*)d_in[3];
  const float* bq = (const float*)d_in[4];
  const float* wk = (const float*)d_in[5];
  const float* bk = (const float*)d_in[6];
  const float* wv = (const float*)d_in[7];
  const float* bv = (const float*)d_in[8];
  const float* wo = (const float*)d_in[9];
  const float* bo = (const float*)d_in[10];
  float* out = (float*)d_out;

  unsigned short* xbf  = (unsigned short*)d_ws;          // 4M shorts (tiled)
  unsigned short* wqkv = xbf  + (size_t)4 * 1024 * 1024; // 3M (tiled)
  unsigned short* wobf = wqkv + (size_t)3 * 1024 * 1024; // 1M (linear)
  unsigned short* qbf  = wobf + (size_t)1 * 1024 * 1024; // 4M (bh,s,d)
  unsigned short* kbf  = qbf  + (size_t)4 * 1024 * 1024; // 4M (tiled frag-major)
  unsigned short* vbf  = kbf  + (size_t)4 * 1024 * 1024; // 4M (V^T tiled)
  unsigned short* obf  = vbf  + (size_t)4 * 1024 * 1024; // 4M (b,s,h*64+d)

  hipLaunchKernelGGL(cast_x_tiled_kernel, dim3(2048), dim3(256), 0, stream, x, xbf);
  hipLaunchKernelGGL(cast_w_tiled_kernel, dim3(1536), dim3(256), 0, stream,
                     wq, wk, wv, wqkv);
  hipLaunchKernelGGL(cast_kernel, dim3(1024), dim3(256), 0, stream, wo, wobf, 262144);

  hipLaunchKernelGGL(qkv_gemm_kernel, dim3(24, 32), dim3(256), 0, stream,
                     xbf, wqkv, bq, bk, bv, cp, sp, qbf, kbf, vbf);
  hipLaunchKernelGGL(flash_kernel, dim3(32, 32), dim3(256), 0, stream,
                     qbf, kbf, vbf, obf);
  hipLaunchKernelGGL(oproj_gemm_kernel, dim3(8, 64), dim3(256), 0, stream,
                     obf, wobf, bo, out);
}

// Round 12
// 200.314 us; speedup vs baseline: 1.2437x; 1.0472x over previous
//
#include <hip/hip_runtime.h>
#include <stdint.h>
#include <stddef.h>

// ============================================================================
// MHA block on gfx950, bf16 MFMA pipeline.  B=2,S=2048,D=1024,H=16,hd=64.
// R17: extend the proven recipe (frag-major tiled global layout + LDS-free
// barrier-free MFMA + ping-pong register pipeline; R15/R16: qkv 68.7->50.5us)
// to oproj, and fuse the three cast kernels into one.
//  - flash epilogue now writes obf in TILED frag-major (panel=s>>7, kt=h,
//    kc=jo*2+(lm>>3), L=((qt&1)*4+w)*128+kc*16+quad*4+r, short=lm&7) --
//    byte-for-byte the layout oproj's A-fragment reads expect (same identity
//    as xbf).  Same 16 stores/lane, now 16B-stride instead of 2KB.
//  - oproj: LDS-free, barrier-free, 64x128 tiles, grid (8,64)=512 blocks
//    (2/CU), ping-pong half-tile pipeline, launch_bounds(256,2) (~100 VGPR).
//  - casts fused: 1M threads, range-split {x tiled | wqkv tiled | wo tiled};
//    6 launches -> 4.
//  - qkv / flash core: byte-identical to R16 (209.8us best).
// Predictions: oproj LDS 0 / ~15us; total 209.8 -> ~192-200us.
// MFMA layouts (verified m89/m91/m120):
//   A-frag: A[m=lane&15][k=(lane>>4)*8+j]  (16B/lane contiguous)
//   B-frag: B[k=(lane>>4)*8+j][n=lane&15] == row-major read of B^T tile
//   C/D:    col=lane&15, row=(lane>>4)*4+reg
// Tiled layout: addr(panel,kt,L) = ((panel*16+kt)*1024 + L)*8 shorts, with
//   L(row,kc) = (row>>4)*128 + kc*16 + (row&15), kc=(k&63)>>3.
// ============================================================================

typedef __bf16 bf16x8 __attribute__((ext_vector_type(8)));
typedef float  f32x4  __attribute__((ext_vector_type(4)));

__device__ __forceinline__ unsigned short f2b(float f) {
  union { float f; uint32_t u; } v; v.f = f;
  uint32_t u = v.u;
  return (unsigned short)((u + 0x7FFFu + ((u >> 16) & 1u)) >> 16);  // RNE
}

// ---------------- fused cast: x, wq/wk/wv, wo -> bf16 frag-major tiled ----
// 1M threads.  i<524288: x (32 panels); i<917504: wqkv (24 panels);
// else: wo (8 panels).  Each thread: read 8 consecutive f32 of (row,k0),
// write one 8-short chunk.
__global__ void cast_all_kernel(const float* __restrict__ x,
                                const float* __restrict__ wq,
                                const float* __restrict__ wk,
                                const float* __restrict__ wv,
                                const float* __restrict__ wo,
                                unsigned short* __restrict__ xbf,
                                unsigned short* __restrict__ wqkv,
                                unsigned short* __restrict__ wobf) {
  int i = blockIdx.x * blockDim.x + threadIdx.x;   // 0..1048575
  const float* src;
  unsigned short* dst;
  int rem;
  if (i < 524288) {                // x: 32 panels x 16 kt x 1024 L
    src = x; dst = xbf; rem = i;
  } else if (i < 917504) {         // wqkv: 3 mats x 8 panels
    rem = i - 524288;
    const int mat = rem >> 17;
    src = (mat == 0) ? wq : (mat == 1) ? wk : wv;
    dst = wqkv;
    // fallthrough uses rem's low 17 bits for in-matrix addr; dst offset below
  } else {                         // wo: 8 panels
    rem = i - 917504;
    src = wo; dst = wobf;
  }
  const int inmat = (i < 524288) ? rem : (i < 917504) ? (rem & 131071) : rem;
  const int L  = inmat & 1023;
  const int kt = (inmat >> 10) & 15;
  const int pn = inmat >> 14;
  const int row = pn * 128 + ((L >> 7) << 4) + (L & 15);
  const int k0  = kt * 64 + ((L >> 4) & 7) * 8;
  const float4* s = (const float4*)(src + (size_t)row * 1024 + k0);
  float4 a = s[0], b = s[1];
  uint4 pk;
  pk.x = (uint32_t)f2b(a.x) | ((uint32_t)f2b(a.y) << 16);
  pk.y = (uint32_t)f2b(a.z) | ((uint32_t)f2b(a.w) << 16);
  pk.z = (uint32_t)f2b(b.x) | ((uint32_t)f2b(b.y) << 16);
  pk.w = (uint32_t)f2b(b.z) | ((uint32_t)f2b(b.w) << 16);
  const size_t oidx = (i < 524288) ? (size_t)rem
                    : (i < 917504) ? (size_t)rem      // wqkv: mat folded in rem
                    : (size_t)rem;
  *(uint4*)(dst + oidx * 8) = pk;
}

// ---------------- fused QKV projection GEMM (+bias, +RoPE on q/k) ----------
// R16-proven: LDS-free, barrier-free, cross-half register-prefetch pipeline.
// Output layouts:
//   q: [bh][2048][64] row-major (RoPE'd)
//   k: tiled frag-major: [bh][st=32][ chunk L = (d>>3)*64 + (s&63) ][8 of d]
//   v: V^T tiled frag-major: [bh][st=32][ chunk L = ((s&63)>>3)*64 + d ][8 of s]
__global__ __launch_bounds__(256, 3) void qkv_gemm_kernel(
    const unsigned short* __restrict__ A,    // x_bf TILED [32 pn][16 kt][1024 L][8]
    const unsigned short* __restrict__ W,    // wqkv TILED [24 pn][16 kt][1024 L][8]
    const float* __restrict__ biasq, const float* __restrict__ biask,
    const float* __restrict__ biasv,
    const float* __restrict__ cp, const float* __restrict__ sp,  // [2048][32]
    unsigned short* __restrict__ qo,
    unsigned short* __restrict__ ko,
    unsigned short* __restrict__ vo)
{
  const int tid  = threadIdx.x;
  const int w    = tid >> 6, l = tid & 63;
  const int lm   = l & 15,  quad = l >> 4;
  const int nblk = blockIdx.x;               // 0..23
  const int m0   = blockIdx.y * 128;
  const int wm   = (w >> 1) * 64, wn = (w & 1) * 64;

  const unsigned short* At = A + (size_t)blockIdx.y * 16 * 8192;  // m-panel
  const unsigned short* Wt = W + (size_t)nblk * 16 * 8192;        // n-panel

  const f32x4 fzero = {0.f, 0.f, 0.f, 0.f};
  f32x4 acc[4][4];
#pragma unroll
  for (int i = 0; i < 4; ++i)
#pragma unroll
    for (int j = 0; j < 4; ++j) acc[i][j] = fzero;

  bf16x8 pA[4], pB[4], qA[4], qB[4];         // two 8-frag ping-pong sets

#define QKV_LOADH(DA, DB, T, KK)                                              \
  {                                                                           \
    const unsigned short* Ab_ = At + (size_t)(T) * 8192;                      \
    const unsigned short* Wb_ = Wt + (size_t)(T) * 8192;                      \
    _Pragma("unroll")                                                         \
    for (int i = 0; i < 4; ++i)                                               \
      DA[i] = *(const bf16x8*)(Ab_ +                                          \
          (size_t)((((w >> 1) * 4 + i) * 128 + (KK) * 64 + l)) * 8);          \
    _Pragma("unroll")                                                         \
    for (int j = 0; j < 4; ++j)                                               \
      DB[j] = *(const bf16x8*)(Wb_ +                                          \
          (size_t)((((w & 1) * 4 + j) * 128 + (KK) * 64 + l)) * 8);           \
  }

#define QKV_MFMAH(SA, SB)                                                     \
  _Pragma("unroll")                                                           \
  for (int i = 0; i < 4; ++i)                                                 \
    _Pragma("unroll")                                                         \
    for (int j = 0; j < 4; ++j)                                               \
      acc[i][j] = __builtin_amdgcn_mfma_f32_16x16x32_bf16(SA[i], SB[j],       \
                                                          acc[i][j], 0, 0, 0);

  QKV_LOADH(pA, pB, 0, 0);                   // prologue: tile 0, half kk=0
#pragma unroll 1
  for (int t = 0; t < 16; ++t) {
    QKV_LOADH(qA, qB, t, 1);                 // issue kk=1 loads...
    QKV_MFMAH(pA, pB);                       // ...under kk=0 MFMAs
    if (t < 15) QKV_LOADH(pA, pB, t + 1, 0); // issue next tile's kk=0...
    QKV_MFMAH(qA, qB);                       // ...under kk=1 MFMAs
  }
#undef QKV_LOADH
#undef QKV_MFMAH

  const int which = nblk >> 3;               // 0=q 1=k 2=v
  const int n0    = (nblk & 7) * 128;
  const float* bias = (which == 0) ? biasq : (which == 1) ? biask : biasv;
#pragma unroll
  for (int i = 0; i < 4; ++i) {
#pragma unroll
    for (int j = 0; j < 4; ++j) {
      const int n = n0 + wn + j * 16 + lm;
      const float bval = bias[n];
      const int h = n >> 6, d = n & 63;
      float vals[4];
#pragma unroll
      for (int r = 0; r < 4; ++r) {
        const int m = m0 + wm + i * 16 + quad * 4 + r;
        const int srow = m & 2047;
        float val = acc[i][j][r] + bval;
        if (which != 2) {
          const float c  = cp[srow * 32 + (d >> 1)];
          const float sn = sp[srow * 32 + (d >> 1)];
          const float part = __shfl_xor(val, 1, 64);
          val = (d & 1) ? (part * sn + val * c) : (val * c - part * sn);
        }
        vals[r] = val;
      }
      const int mbase = m0 + wm + i * 16 + quad * 4;   // 4 consecutive s
      const int b = mbase >> 11, s0 = mbase & 2047;
      const int bh = (b << 4) + h;
      if (which == 0) {
#pragma unroll
        for (int r = 0; r < 4; ++r)
          qo[((size_t)bh * 2048 + s0 + r) * 64 + d] = f2b(vals[r]);
      } else if (which == 1) {
        // tiled: base = (bh*32 + s>>6)*4096 + ((d>>3)*64 + (s&63))*8 + (d&7)
#pragma unroll
        for (int r = 0; r < 4; ++r) {
          const int s = s0 + r;
          ko[((size_t)bh * 32 + (s >> 6)) * 4096 +
             (size_t)(((d >> 3) * 64 + (s & 63))) * 8 + (d & 7)] = f2b(vals[r]);
        }
      } else {
        // V^T tiled, 4 consecutive s -> one uint2 (8B) store
        uint32_t w0 = (uint32_t)f2b(vals[0]) | ((uint32_t)f2b(vals[1]) << 16);
        uint32_t w1 = (uint32_t)f2b(vals[2]) | ((uint32_t)f2b(vals[3]) << 16);
        uint2 pk; pk.x = w0; pk.y = w1;
        *(uint2*)(vo + ((size_t)bh * 32 + (s0 >> 6)) * 4096 +
                  (size_t)((((s0 & 63) >> 3) * 64 + d)) * 8 + (s0 & 7)) = pk;
      }
    }
  }
}

// ---------------- flash attention (R14/R15/R16-proven core) ---------------
// grid (bh=32, 32); block 256 thr = 4 waves; block covers 64 q-rows.
// R17: epilogue writes obf in TILED frag-major for oproj's direct A-reads.
__global__ __launch_bounds__(256, 4) void flash_kernel(
    const unsigned short* __restrict__ Q,    // [32][2048][64] row-major
    const unsigned short* __restrict__ K,    // tiled frag-major (see qkv)
    const unsigned short* __restrict__ VT,   // V^T tiled frag-major
    unsigned short* __restrict__ O)          // obf TILED [32 pn][16 kt][1024 L][8]
{
  constexpr int PSTRIDE = 72;                // Ps row stride (shorts)
  __shared__ unsigned short Ps[64 * PSTRIDE];    // 9 KB (only LDS)
  const int tid = threadIdx.x;
  const int w = tid >> 6, l = tid & 63, lm = l & 15, quad = l >> 4;
  const int bh = blockIdx.x, qt = 31 - (int)blockIdx.y;  // heavy first
  const int row0 = qt * 64 + w * 16;         // wave's first q-row

  // Q fragments: lane reads row row0+lm, 8 d at kc*32+quad*8
  bf16x8 aq[2];
#pragma unroll
  for (int kc = 0; kc < 2; ++kc)
    aq[kc] = *(const bf16x8*)(Q + ((size_t)bh * 2048 + row0 + lm) * 64 + kc * 32 + quad * 8);

  const f32x4 fzero = {0.f, 0.f, 0.f, 0.f};
  f32x4 Oacc[4];
#pragma unroll
  for (int jo = 0; jo < 4; ++jo) Oacc[jo] = fzero;
  float m_i = -1e30f, l_i = 0.f;

  const int nkv = qt + 1;

  // ---- unmasked tiles 0 .. qt-1 ----
#pragma unroll 1
  for (int kt = 0; kt < nkv - 1; ++kt) {
    const size_t tbase = ((size_t)bh * 32 + kt) * 4096;
    bf16x8 kf[2][4], vf[2][4];
#pragma unroll
    for (int kc = 0; kc < 2; ++kc)
#pragma unroll
      for (int tb = 0; tb < 4; ++tb) {
        const size_t off = tbase + (size_t)(((kc * 4 + quad) * 64 + tb * 16 + lm)) * 8;
        kf[kc][tb] = *(const bf16x8*)(K + off);
        vf[kc][tb] = *(const bf16x8*)(VT + off);
      }
    // S^T = K * Q^T : Sc[tb] holds t = tb*16+quad*4+r (rows), m = lm (col)
    f32x4 Sc[4];
#pragma unroll
    for (int tb = 0; tb < 4; ++tb) Sc[tb] = fzero;
#pragma unroll
    for (int kc = 0; kc < 2; ++kc)
#pragma unroll
      for (int tb = 0; tb < 4; ++tb)
        Sc[tb] = __builtin_amdgcn_mfma_f32_16x16x32_bf16(kf[kc][tb], aq[kc], Sc[tb], 0, 0, 0);

    float mx = -1e30f;
#pragma unroll
    for (int tb = 0; tb < 4; ++tb)
#pragma unroll
      for (int r = 0; r < 4; ++r) {
        float s = Sc[tb][r] * 0.125f;        // 1/sqrt(64)
        Sc[tb][r] = s;
        mx = fmaxf(mx, s);
      }
    mx = fmaxf(mx, __shfl_xor(mx, 16, 64));
    mx = fmaxf(mx, __shfl_xor(mx, 32, 64));

    // T13 defer-max: skip rescale when all rows grew by <= 8
    const bool skip = (bool)__all(mx - m_i <= 8.0f);
    float alpha = 1.f;
    if (!skip) {
      const float mnew = fmaxf(m_i, mx);
      alpha = __expf(m_i - mnew);
      m_i = mnew;
    }
    const float mref = m_i;

    float ps = 0.f;
#pragma unroll
    for (int tb = 0; tb < 4; ++tb) {
      float p0 = __expf(Sc[tb][0] - mref), p1 = __expf(Sc[tb][1] - mref);
      float p2 = __expf(Sc[tb][2] - mref), p3 = __expf(Sc[tb][3] - mref);
      ps += (p0 + p1) + (p2 + p3);
      uint2 pk;
      pk.x = (uint32_t)f2b(p0) | ((uint32_t)f2b(p1) << 16);
      pk.y = (uint32_t)f2b(p2) | ((uint32_t)f2b(p3) << 16);
      *(uint2*)(Ps + (size_t)(w * 16 + lm) * PSTRIDE + tb * 16 + quad * 4) = pk;
    }
    ps += __shfl_xor(ps, 16, 64);
    ps += __shfl_xor(ps, 32, 64);
    if (skip) {
      l_i += ps;
    } else {
      l_i = l_i * alpha + ps;
      float af4[4];
#pragma unroll
      for (int r = 0; r < 4; ++r) af4[r] = __shfl(alpha, quad * 4 + r, 64);
#pragma unroll
      for (int jo = 0; jo < 4; ++jo)
#pragma unroll
        for (int r = 0; r < 4; ++r) Oacc[jo][r] *= af4[r];
    }

    // O += P V
#pragma unroll
    for (int kc = 0; kc < 2; ++kc) {
      bf16x8 ap = *(const bf16x8*)(Ps + (size_t)(w * 16 + lm) * PSTRIDE + kc * 32 + quad * 8);
#pragma unroll
      for (int jo = 0; jo < 4; ++jo)
        Oacc[jo] = __builtin_amdgcn_mfma_f32_16x16x32_bf16(ap, vf[kc][jo], Oacc[jo], 0, 0, 0);
    }
  }

  // ---- diagonal (masked) tile kt = qt ----
  {
    const size_t tbase = ((size_t)bh * 32 + qt) * 4096;
    bf16x8 kf[2][4], vf[2][4];
#pragma unroll
    for (int kc = 0; kc < 2; ++kc)
#pragma unroll
      for (int tb = 0; tb < 4; ++tb) {
        const size_t off = tbase + (size_t)(((kc * 4 + quad) * 64 + tb * 16 + lm)) * 8;
        kf[kc][tb] = *(const bf16x8*)(K + off);
        vf[kc][tb] = *(const bf16x8*)(VT + off);
      }
    f32x4 Sc[4];
#pragma unroll
    for (int tb = 0; tb < 4; ++tb) Sc[tb] = fzero;
#pragma unroll
    for (int kc = 0; kc < 2; ++kc)
#pragma unroll
      for (int tb = 0; tb < 4; ++tb)
        Sc[tb] = __builtin_amdgcn_mfma_f32_16x16x32_bf16(kf[kc][tb], aq[kc], Sc[tb], 0, 0, 0);

    const int mrel = w * 16 + lm;            // mask t-index > mrel
    float mx = -1e30f;
#pragma unroll
    for (int tb = 0; tb < 4; ++tb)
#pragma unroll
      for (int r = 0; r < 4; ++r) {
        float s = Sc[tb][r] * 0.125f;
        if (tb * 16 + quad * 4 + r > mrel) s = -1e30f;
        Sc[tb][r] = s;
        mx = fmaxf(mx, s);
      }
    mx = fmaxf(mx, __shfl_xor(mx, 16, 64));
    mx = fmaxf(mx, __shfl_xor(mx, 32, 64));
    const float mnew  = fmaxf(m_i, mx);
    const float alpha = __expf(m_i - mnew);
    m_i = mnew;

    float ps = 0.f;
#pragma unroll
    for (int tb = 0; tb < 4; ++tb) {
      float p0 = __expf(Sc[tb][0] - mnew), p1 = __expf(Sc[tb][1] - mnew);
      float p2 = __expf(Sc[tb][2] - mnew), p3 = __expf(Sc[tb][3] - mnew);
      ps += (p0 + p1) + (p2 + p3);
      uint2 pk;
      pk.x = (uint32_t)f2b(p0) | ((uint32_t)f2b(p1) << 16);
      pk.y = (uint32_t)f2b(p2) | ((uint32_t)f2b(p3) << 16);
      *(uint2*)(Ps + (size_t)(w * 16 + lm) * PSTRIDE + tb * 16 + quad * 4) = pk;
    }
    ps += __shfl_xor(ps, 16, 64);
    ps += __shfl_xor(ps, 32, 64);
    l_i = l_i * alpha + ps;

    float af4[4];
#pragma unroll
    for (int r = 0; r < 4; ++r) af4[r] = __shfl(alpha, quad * 4 + r, 64);
#pragma unroll
    for (int jo = 0; jo < 4; ++jo)
#pragma unroll
      for (int r = 0; r < 4; ++r) Oacc[jo][r] *= af4[r];

#pragma unroll
    for (int kc = 0; kc < 2; ++kc) {
      bf16x8 ap = *(const bf16x8*)(Ps + (size_t)(w * 16 + lm) * PSTRIDE + kc * 32 + quad * 8);
#pragma unroll
      for (int jo = 0; jo < 4; ++jo)
        Oacc[jo] = __builtin_amdgcn_mfma_f32_16x16x32_bf16(ap, vf[kc][jo], Oacc[jo], 0, 0, 0);
    }
  }

  // epilogue: normalize, write obf TILED frag-major.
  // s_global = b*2048 + qt*64 + w*16 + quad*4 + r; col = h*64 + jo*16 + lm.
  // panel = b*16 + (qt>>1); kt = h; L = ((qt&1)*4+w)*128 + (jo*2+(lm>>3))*16
  //         + quad*4 + r; short = lm&7.
  float lf[4];
#pragma unroll
  for (int r = 0; r < 4; ++r) lf[r] = 1.0f / __shfl(l_i, quad * 4 + r, 64);
  const int b = bh >> 4, h = bh & 15;
  const size_t obase = ((size_t)((b * 16 + (qt >> 1)) * 16 + h)) * 8192;
  const int Lbase = ((qt & 1) * 4 + w) * 128 + quad * 4;
#pragma unroll
  for (int jo = 0; jo < 4; ++jo) {
    const int Ljo = Lbase + (jo * 2 + (lm >> 3)) * 16;
#pragma unroll
    for (int r = 0; r < 4; ++r)
      O[obase + (size_t)(Ljo + r) * 8 + (lm & 7)] = f2b(Oacc[jo][r] * lf[r]);
  }
}

// ---------------- output projection GEMM (R17: R16-recipe) ----------------
// out[4096,1024] = Obf_tiled @ Wo_tiled^T + bias (fp32 out).
// LDS-free, barrier-free, 64x128 tiles, grid (8,64)=512 blocks (2/CU),
// ping-pong half-tile register pipeline.
__global__ __launch_bounds__(256, 2) void oproj_gemm_kernel(
    const unsigned short* __restrict__ A,    // obf TILED [32 pn][16 kt][1024 L][8]
    const unsigned short* __restrict__ W,    // wobf TILED [8 pn][16 kt][1024 L][8]
    const float* __restrict__ bias,
    float* __restrict__ out)
{
  const int tid = threadIdx.x;
  const int w = tid >> 6, l = tid & 63;
  const int lm = l & 15, quad = l >> 4;
  const int nblk = blockIdx.x;               // 0..7
  const int m0 = blockIdx.y * 64;            // 64-row m-tile
  const int half = blockIdx.y & 1;

  const unsigned short* At = A + (size_t)(blockIdx.y >> 1) * 16 * 8192;
  const unsigned short* Wt = W + (size_t)nblk * 16 * 8192;

  const f32x4 fzero = {0.f, 0.f, 0.f, 0.f};
  f32x4 acc[4][2];
#pragma unroll
  for (int i = 0; i < 4; ++i)
#pragma unroll
    for (int j = 0; j < 2; ++j) acc[i][j] = fzero;

  bf16x8 pA[4], pB[2], qA[4], qB[2];

#define OP_LOADH(DA, DB, T, KK)                                               \
  {                                                                           \
    const unsigned short* Ab_ = At + (size_t)(T) * 8192;                      \
    const unsigned short* Wb_ = Wt + (size_t)(T) * 8192;                      \
    _Pragma("unroll")                                                         \
    for (int i = 0; i < 4; ++i)                                               \
      DA[i] = *(const bf16x8*)(Ab_ +                                          \
          (size_t)(((half * 4 + i) * 128 + (KK) * 64 + l)) * 8);              \
    _Pragma("unroll")                                                         \
    for (int j = 0; j < 2; ++j)                                               \
      DB[j] = *(const bf16x8*)(Wb_ +                                          \
          (size_t)(((w * 2 + j) * 128 + (KK) * 64 + l)) * 8);                 \
  }

#define OP_MFMAH(SA, SB)                                                      \
  _Pragma("unroll")                                                           \
  for (int i = 0; i < 4; ++i)                                                 \
    _Pragma("unroll")                                                         \
    for (int j = 0; j < 2; ++j)                                               \
      acc[i][j] = __builtin_amdgcn_mfma_f32_16x16x32_bf16(SA[i], SB[j],       \
                                                          acc[i][j], 0, 0, 0);

  OP_LOADH(pA, pB, 0, 0);
#pragma unroll 1
  for (int t = 0; t < 16; ++t) {
    OP_LOADH(qA, qB, t, 1);
    OP_MFMAH(pA, pB);
    if (t < 15) OP_LOADH(pA, pB, t + 1, 0);
    OP_MFMAH(qA, qB);
  }
#undef OP_LOADH
#undef OP_MFMAH

#pragma unroll
  for (int i = 0; i < 4; ++i) {
#pragma unroll
    for (int j = 0; j < 2; ++j) {
      const int n = nblk * 128 + w * 32 + j * 16 + lm;
      const float bval = bias[n];
#pragma unroll
      for (int r = 0; r < 4; ++r) {
        const int m = m0 + i * 16 + quad * 4 + r;
        out[(size_t)m * 1024 + n] = acc[i][j][r] + bval;
      }
    }
  }
}

// ---------------- host launch ----------------
extern "C" void kernel_launch(void* const* d_in, const int* in_sizes, int n_in,
                              void* d_out, int out_size, void* d_ws, size_t ws_size,
                              hipStream_t stream) {
  (void)in_sizes; (void)n_in; (void)out_size; (void)ws_size;
  const float* x  = (const float*)d_in[0];
  const float* cp = (const float*)d_in[1];
  const float* sp = (const float*)d_in[2];
  const float* wq = (const float*)d_in[3];
  const float* bq = (const float*)d_in[4];
  const float* wk = (const float*)d_in[5];
  const float* bk = (const float*)d_in[6];
  const float* wv = (const float*)d_in[7];
  const float* bv = (const float*)d_in[8];
  const float* wo = (const float*)d_in[9];
  const float* bo = (const float*)d_in[10];
  float* out = (float*)d_out;

  unsigned short* xbf  = (unsigned short*)d_ws;          // 4M shorts (tiled)
  unsigned short* wqkv = xbf  + (size_t)4 * 1024 * 1024; // 3M (tiled)
  unsigned short* wobf = wqkv + (size_t)3 * 1024 * 1024; // 1M (tiled)
  unsigned short* qbf  = wobf + (size_t)1 * 1024 * 1024; // 4M (bh,s,d)
  unsigned short* kbf  = qbf  + (size_t)4 * 1024 * 1024; // 4M (tiled frag-major)
  unsigned short* vbf  = kbf  + (size_t)4 * 1024 * 1024; // 4M (V^T tiled)
  unsigned short* obf  = vbf  + (size_t)4 * 1024 * 1024; // 4M (tiled frag-major)

  hipLaunchKernelGGL(cast_all_kernel, dim3(4096), dim3(256), 0, stream,
                     x, wq, wk, wv, wo, xbf, wqkv, wobf);

  hipLaunchKernelGGL(qkv_gemm_kernel, dim3(24, 32), dim3(256), 0, stream,
                     xbf, wqkv, bq, bk, bv, cp, sp, qbf, kbf, vbf);
  hipLaunchKernelGGL(flash_kernel, dim3(32, 32), dim3(256), 0, stream,
                     qbf, kbf, vbf, obf);
  hipLaunchKernelGGL(oproj_gemm_kernel, dim3(8, 64), dim3(256), 0, stream,
                     obf, wobf, bo, out);
}